// Round 1
// baseline (672.327 us; speedup 1.0000x reference)
//
#include <hip/hip_runtime.h>
#include <cstdint>
#include <cstddef>

typedef __attribute__((ext_vector_type(8))) short short8;
typedef __attribute__((ext_vector_type(4))) short short4v;
typedef __attribute__((ext_vector_type(4))) float f32x4;
typedef unsigned short u16;

#define DI __device__ __forceinline__

// ---------------- problem constants ----------------
constexpr int BATCH = 4;
constexpr int TT = 8, HHs = 14, WWs = 14;
constexpr int HEADS = 12, HD = 64;
constexpr int NTOK = 1569;          // T*H*W + 1
constexpr int NPAD = 1600;          // 25 * 64
constexpr int DIM = 768, DIM3 = 2304;
constexpr int MROWS = BATCH * NTOK; // 6276
constexpr int MP = 6400;            // 50 * 128
constexpr int AUG = 128;            // 64 ch + 8 + 14 + 14 + pad
constexpr int BHN = BATCH * HEADS;  // 48
constexpr float SCALE = 0.125f;
constexpr float LN_EPS = 1e-5f;

// ---------------- helpers ----------------
DI u16 f2bf(float x) {
  union { float f; unsigned u; } v; v.f = x;
  unsigned r = v.u + 0x7FFFu + ((v.u >> 16) & 1u);
  return (u16)(r >> 16);
}
DI float bf2f(u16 h) {
  union { unsigned u; float f; } v; v.u = ((unsigned)h) << 16;
  return v.f;
}

typedef const __attribute__((address_space(1))) unsigned int gu32;
typedef __attribute__((address_space(3))) unsigned int lu32;
DI void gld16(const void* g, void* l) {
  __builtin_amdgcn_global_load_lds((gu32*)g, (lu32*)l, 16, 0, 0);
}

// ---------------- cast kernels ----------------
__global__ __launch_bounds__(256) void k_cast_x(const float* __restrict__ x,
                                                u16* __restrict__ xb) {
  int i = (blockIdx.x * 256 + threadIdx.x) * 4;
  if (i >= MP * DIM) return;
  int row = i / DIM;
  short4v o;
  if (row < MROWS) {
    float4 v = *(const float4*)(x + i);
    o.x = (short)f2bf(v.x); o.y = (short)f2bf(v.y);
    o.z = (short)f2bf(v.z); o.w = (short)f2bf(v.w);
  } else {
    o.x = 0; o.y = 0; o.z = 0; o.w = 0;
  }
  *(short4v*)(xb + i) = o;
}

// dst (NC, K) bf16 = transpose of src (K, NC) f32
__global__ __launch_bounds__(256) void k_transpose_cast(const float* __restrict__ src,
                                                        u16* __restrict__ dst,
                                                        int K, int NC) {
  int i = blockIdx.x * 256 + threadIdx.x;
  if (i >= K * NC) return;
  int n = i / K, k = i - n * K;
  dst[i] = f2bf(src[(size_t)k * NC + n]);
}

// ---------------- GEMM: C(M,N) = A(M,768)*Bt(N,768)^T + bias ----------------
// EPI 0: scatter to qkv ws f32 (t,b,h,n,c).  EPI 1: linear f32 out (proj).
template <int EPI>
__global__ __launch_bounds__(256) void k_gemm(const u16* __restrict__ A,
                                              const u16* __restrict__ Bt,
                                              const float* __restrict__ bias,
                                              float* __restrict__ out) {
  __shared__ __align__(16) u16 sA[128 * 64];
  __shared__ __align__(16) u16 sB[128 * 64];
  const int tid = threadIdx.x;
  const int w = tid >> 6, lane = tid & 63;
  const int g = lane >> 4, lr = lane & 15;
  const int brow = blockIdx.x * 128, bcol = blockIdx.y * 128;
  const int wr = w >> 1, wc = w & 1;

  f32x4 acc[4][4];
#pragma unroll
  for (int m = 0; m < 4; ++m)
#pragma unroll
    for (int n = 0; n < 4; ++n) {
      acc[m][n].x = 0.f; acc[m][n].y = 0.f; acc[m][n].z = 0.f; acc[m][n].w = 0.f;
    }

  for (int kt = 0; kt < 12; ++kt) {
    __syncthreads();
#pragma unroll
    for (int j = 0; j < 4; ++j) {
      int cb = (j * 4 + w) * 64;
      int chunk = cb + lane;
      int row = chunk >> 3, ch = chunk & 7;
      int gch = ch ^ (row & 7);
      gld16(A + (size_t)(brow + row) * DIM + kt * 64 + gch * 8, &sA[cb * 8]);
      gld16(Bt + (size_t)(bcol + row) * DIM + kt * 64 + gch * 8, &sB[cb * 8]);
    }
    __syncthreads();

    short8 af[4][2], bfr[4][2];
#pragma unroll
    for (int m = 0; m < 4; ++m) {
      int row = wr * 64 + m * 16 + lr;
      int sw = row & 7;
#pragma unroll
      for (int ks = 0; ks < 2; ++ks)
        af[m][ks] = *(const short8*)&sA[row * 64 + (((ks * 4 + g) ^ sw) * 8)];
    }
#pragma unroll
    for (int n = 0; n < 4; ++n) {
      int row = wc * 64 + n * 16 + lr;
      int sw = row & 7;
#pragma unroll
      for (int ks = 0; ks < 2; ++ks)
        bfr[n][ks] = *(const short8*)&sB[row * 64 + (((ks * 4 + g) ^ sw) * 8)];
    }
#pragma unroll
    for (int m = 0; m < 4; ++m)
#pragma unroll
      for (int n = 0; n < 4; ++n) {
        acc[m][n] = __builtin_amdgcn_mfma_f32_16x16x32_bf16(af[m][0], bfr[n][0], acc[m][n], 0, 0, 0);
        acc[m][n] = __builtin_amdgcn_mfma_f32_16x16x32_bf16(af[m][1], bfr[n][1], acc[m][n], 0, 0, 0);
      }
  }

#pragma unroll
  for (int m = 0; m < 4; ++m)
#pragma unroll
    for (int n = 0; n < 4; ++n) {
      int gj = bcol + wc * 64 + n * 16 + lr;
      float bv = bias[gj];
#pragma unroll
      for (int r = 0; r < 4; ++r) {
        int gm = brow + wr * 64 + m * 16 + g * 4 + r;
        if (gm >= MROWS) continue;
        float v = acc[m][n][r] + bv;
        if (EPI == 0) {
          int t = gj >= 1536 ? 2 : (gj >= 768 ? 1 : 0);
          int rem = gj - t * 768;
          int h = rem >> 6, c = rem & 63;
          int b = gm >= 3 * NTOK ? 3 : (gm >= 2 * NTOK ? 2 : (gm >= NTOK ? 1 : 0));
          int nt = gm - b * NTOK;
          out[(((size_t)(t * BATCH + b) * HEADS + h) * NPAD + nt) * HD + c] = v;
        } else {
          out[(size_t)gm * DIM + gj] = v;
        }
      }
    }
}

// ---------------- pool (depthwise conv3d) + LN + rel rows + aug writes ----------------
__global__ __launch_bounds__(256) void k_pool(
    const float* __restrict__ qkv,
    const float* __restrict__ pw_q, const float* __restrict__ pw_k, const float* __restrict__ pw_v,
    const float* __restrict__ nw_q, const float* __restrict__ nb_q,
    const float* __restrict__ nw_k, const float* __restrict__ nb_k,
    const float* __restrict__ nw_v, const float* __restrict__ nb_v,
    const float* __restrict__ rel_t, const float* __restrict__ rel_h, const float* __restrict__ rel_w,
    u16* __restrict__ Qa, u16* __restrict__ Ka, u16* __restrict__ Vt) {
  __shared__ __align__(16) float sQv[4][64];
  const int wv = threadIdx.x >> 6, lane = threadIdx.x & 63;
  int unit = blockIdx.x * 4 + wv;
  const int tau = unit / (BHN * NPAD);
  int rem = unit - tau * (BHN * NPAD);
  const int bh = rem / NPAD, n = rem - bh * NPAD;

  if (n >= NTOK) {  // zero pad rows
    if (tau == 0) {
      size_t base = (size_t)(bh * NPAD + n) * AUG;
      Qa[base + lane] = 0; Qa[base + 64 + lane] = 0;
    } else if (tau == 1) {
      size_t base = (size_t)(bh * NPAD + n) * AUG;
      Ka[base + lane] = 0; Ka[base + 64 + lane] = 0;
    } else {
      Vt[((size_t)bh * HD + lane) * NPAD + n] = 0;
    }
    return;
  }

  const float* src = qkv + ((size_t)tau * BHN + bh) * ((size_t)NPAD * HD);
  float val;
  int t = 0, hh = 0, ww = 0;
  if (n == 0) {
    val = src[lane];
  } else {
    int p = n - 1;
    t = p / 196; int pr = p - t * 196; hh = pr / 14; ww = pr - hh * 14;
    const float* wp = (tau == 0 ? pw_q : tau == 1 ? pw_k : pw_v) + lane * 27;
    float a = 0.f;
#pragma unroll
    for (int dt = -1; dt <= 1; ++dt) {
      int tt = t + dt; if ((unsigned)tt >= 8u) continue;
#pragma unroll
      for (int dh = -1; dh <= 1; ++dh) {
        int h2 = hh + dh; if ((unsigned)h2 >= 14u) continue;
#pragma unroll
        for (int dw = -1; dw <= 1; ++dw) {
          int w2 = ww + dw; if ((unsigned)w2 >= 14u) continue;
          a += src[(size_t)(1 + (tt * 14 + h2) * 14 + w2) * HD + lane] *
               wp[(dt + 1) * 9 + (dh + 1) * 3 + (dw + 1)];
        }
      }
    }
    val = a;
  }

  // LayerNorm over 64 channels (wave reduce)
  float s = val, sq = val * val;
#pragma unroll
  for (int off = 1; off < 64; off <<= 1) {
    s += __shfl_xor(s, off);
    sq += __shfl_xor(sq, off);
  }
  float mean = s * (1.f / 64.f);
  float var = sq * (1.f / 64.f) - mean * mean;
  const float* nw = tau == 0 ? nw_q : tau == 1 ? nw_k : nw_v;
  const float* nb = tau == 0 ? nb_q : tau == 1 ? nb_k : nb_v;
  float ln = (val - mean) * rsqrtf(var + LN_EPS) * nw[lane] + nb[lane];

  if (tau == 0) {
    sQv[wv][lane] = ln;
    float dot = 0.f;
    if (n > 0 && lane < 36) {
      const float* Mrow = lane < 8  ? rel_t + (size_t)(t - lane + 7) * HD
                        : lane < 22 ? rel_h + (size_t)(hh - (lane - 8) + 13) * HD
                                    : rel_w + (size_t)(ww - (lane - 22) + 13) * HD;
#pragma unroll
      for (int cc = 0; cc < 16; ++cc) {
        float4 qv = *(const float4*)&sQv[wv][cc * 4];
        float4 mv = *(const float4*)&Mrow[cc * 4];
        dot += qv.x * mv.x + qv.y * mv.y + qv.z * mv.z + qv.w * mv.w;
      }
    }
    size_t base = (size_t)(bh * NPAD + n) * AUG;
    Qa[base + lane] = f2bf(ln * SCALE);
    Qa[base + 64 + lane] = (n > 0 && lane < 36) ? f2bf(dot) : (u16)0;
  } else if (tau == 1) {
    size_t base = (size_t)(bh * NPAD + n) * AUG;
    Ka[base + lane] = f2bf(ln);
    u16 e = 0;
    if (n > 0 && (lane == t || lane == 8 + hh || lane == 22 + ww)) e = 0x3F80;  // bf16 1.0
    Ka[base + 64 + lane] = e;
  } else {
    Vt[((size_t)bh * HD + lane) * NPAD + n] = f2bf(ln);
  }
}

// ---------------- fused flash attention ----------------
__global__ __launch_bounds__(256) void k_attn(const u16* __restrict__ Qa,
                                              const u16* __restrict__ Ka,
                                              const u16* __restrict__ Vt,
                                              u16* __restrict__ outA) {
  __shared__ __align__(16) u16 sK[64 * 128];   // K_aug tile, chunk-swizzled
  __shared__ __align__(16) u16 sV[64 * 64];    // V^T tile [c][key], chunk-swizzled
  __shared__ __align__(16) u16 sP[4][16 * 72]; // per-wave P, padded stride 72
  const int tid = threadIdx.x, w = tid >> 6, lane = tid & 63;
  const int g = lane >> 4, lr = lane & 15;
  const int bh = blockIdx.x / 25, qt = blockIdx.x % 25;
  const int b = bh / HEADS, h = bh - b * HEADS;
  const int q0 = qt * 64 + w * 16;

  short8 aq[4];
  {
    const u16* qrow = Qa + ((size_t)bh * NPAD + q0 + lr) * AUG;
#pragma unroll
    for (int ks = 0; ks < 4; ++ks) aq[ks] = *(const short8*)(qrow + ks * 32 + g * 8);
  }

  f32x4 O[4];
#pragma unroll
  for (int c4 = 0; c4 < 4; ++c4) { O[c4].x = 0.f; O[c4].y = 0.f; O[c4].z = 0.f; O[c4].w = 0.f; }
  float mrun[4], lrun[4];
#pragma unroll
  for (int r = 0; r < 4; ++r) { mrun[r] = -1e30f; lrun[r] = 0.f; }

  for (int kb = 0; kb < 25; ++kb) {
    const u16* Kb = Ka + ((size_t)bh * NPAD + kb * 64) * AUG;
#pragma unroll
    for (int j = 0; j < 4; ++j) {
      int cb = (j * 4 + w) * 64;
      int chunk = cb + lane;
      int row = chunk >> 4, ch = chunk & 15;
      int gch = ch ^ (row & 7);
      gld16(Kb + (size_t)row * AUG + gch * 8, &sK[cb * 8]);
    }
    const u16* Vb = Vt + (size_t)bh * HD * NPAD + kb * 64;
#pragma unroll
    for (int j = 0; j < 2; ++j) {
      int cb = (j * 4 + w) * 64;
      int chunk = cb + lane;
      int row = chunk >> 3, ch = chunk & 7;
      int gch = ch ^ (row & 7);
      gld16(Vb + (size_t)row * NPAD + gch * 8, &sV[cb * 8]);
    }
    __syncthreads();

    // S = Q_aug * K_aug^T  (D layout: row q = g*4+r, col key = lr)
    f32x4 sacc[4];
#pragma unroll
    for (int ct = 0; ct < 4; ++ct) {
      f32x4 a; a.x = 0.f; a.y = 0.f; a.z = 0.f; a.w = 0.f;
      int row = ct * 16 + lr;
      int sw = row & 7;
#pragma unroll
      for (int ks = 0; ks < 4; ++ks) {
        short8 bk = *(const short8*)&sK[row * 128 + (((ks * 4 + g) ^ sw) * 8)];
        a = __builtin_amdgcn_mfma_f32_16x16x32_bf16(aq[ks], bk, a, 0, 0, 0);
      }
      sacc[ct] = a;
    }
    // mask invalid keys
    int key0 = kb * 64 + lr;
#pragma unroll
    for (int ct = 0; ct < 4; ++ct)
      if (key0 + ct * 16 >= NTOK) {
        sacc[ct].x = -1e30f; sacc[ct].y = -1e30f; sacc[ct].z = -1e30f; sacc[ct].w = -1e30f;
      }
    // online softmax per q-row r
#pragma unroll
    for (int r = 0; r < 4; ++r) {
      float mx = fmaxf(fmaxf(sacc[0][r], sacc[1][r]), fmaxf(sacc[2][r], sacc[3][r]));
#pragma unroll
      for (int off = 1; off < 16; off <<= 1) mx = fmaxf(mx, __shfl_xor(mx, off));
      float nm = fmaxf(mrun[r], mx);
      float sc = __expf(mrun[r] - nm);
      mrun[r] = nm;
      float ps = 0.f;
#pragma unroll
      for (int ct = 0; ct < 4; ++ct) {
        float p = __expf(sacc[ct][r] - nm);
        sacc[ct][r] = p;
        ps += p;
      }
#pragma unroll
      for (int off = 1; off < 16; off <<= 1) ps += __shfl_xor(ps, off);
      lrun[r] = lrun[r] * sc + ps;
#pragma unroll
      for (int c4 = 0; c4 < 4; ++c4) O[c4][r] *= sc;
      int qo = g * 4 + r;
#pragma unroll
      for (int ct = 0; ct < 4; ++ct)
        sP[w][qo * 72 + ct * 16 + lr] = f2bf(sacc[ct][r]);
    }
    // O += P * V
#pragma unroll
    for (int kk = 0; kk < 2; ++kk) {
      short8 ap = *(const short8*)&sP[w][lr * 72 + kk * 32 + g * 8];
#pragma unroll
      for (int c4 = 0; c4 < 4; ++c4) {
        int row = c4 * 16 + lr;
        int sw = row & 7;
        short8 bv = *(const short8*)&sV[row * 64 + (((kk * 4 + g) ^ sw) * 8)];
        O[c4] = __builtin_amdgcn_mfma_f32_16x16x32_bf16(ap, bv, O[c4], 0, 0, 0);
      }
    }
    __syncthreads();
  }

  // epilogue: normalize, residual (+pooled q), store bf16
#pragma unroll
  for (int r = 0; r < 4; ++r) {
    int qg = q0 + g * 4 + r;
    if (qg >= NTOK) continue;
    float inv = 1.f / lrun[r];
#pragma unroll
    for (int c4 = 0; c4 < 4; ++c4) {
      float v = O[c4][r] * inv;
      int c = c4 * 16 + lr;
      if (qg >= 1) v += 8.f * bf2f(Qa[((size_t)bh * NPAD + qg) * AUG + c]);
      outA[((size_t)(b * NTOK + qg)) * DIM + h * HD + c] = f2bf(v);
    }
  }
}

// ---------------- launch ----------------
extern "C" void kernel_launch(void* const* d_in, const int* in_sizes, int n_in,
                              void* d_out, int out_size, void* d_ws, size_t ws_size,
                              hipStream_t stream) {
  (void)in_sizes; (void)n_in; (void)out_size; (void)ws_size;
  const float* x      = (const float*)d_in[0];
  const float* qkv_w  = (const float*)d_in[1];
  const float* qkv_b  = (const float*)d_in[2];
  const float* proj_w = (const float*)d_in[3];
  const float* proj_b = (const float*)d_in[4];
  const float* pw_q   = (const float*)d_in[5];
  const float* pw_k   = (const float*)d_in[6];
  const float* pw_v   = (const float*)d_in[7];
  const float* nw_q   = (const float*)d_in[8];
  const float* nb_q   = (const float*)d_in[9];
  const float* nw_k   = (const float*)d_in[10];
  const float* nb_k   = (const float*)d_in[11];
  const float* nw_v   = (const float*)d_in[12];
  const float* nb_v   = (const float*)d_in[13];
  const float* rel_t  = (const float*)d_in[14];
  const float* rel_h  = (const float*)d_in[15];
  const float* rel_w  = (const float*)d_in[16];
  float* out = (float*)d_out;

  char* ws = (char*)d_ws;
  size_t off = 0;
  auto alloc = [&](size_t bytes) -> void* {
    off = (off + 511) & ~(size_t)511;
    void* p = ws + off;
    off += bytes;
    return p;
  };
  u16*   xb     = (u16*)alloc((size_t)MP * DIM * 2);
  u16*   qkvwT  = (u16*)alloc((size_t)DIM3 * DIM * 2);
  u16*   projwT = (u16*)alloc((size_t)DIM * DIM * 2);
  float* qkvf   = (float*)alloc((size_t)3 * BHN * NPAD * HD * 4);
  u16*   Qa     = (u16*)alloc((size_t)BHN * NPAD * AUG * 2);
  u16*   Ka     = (u16*)alloc((size_t)BHN * NPAD * AUG * 2);
  u16*   Vt     = (u16*)alloc((size_t)BHN * HD * NPAD * 2);
  u16*   attnO  = (u16*)alloc((size_t)MP * DIM * 2);

  k_cast_x<<<dim3(MP * DIM / 1024), dim3(256), 0, stream>>>(x, xb);
  k_transpose_cast<<<dim3(DIM3 * DIM / 256), dim3(256), 0, stream>>>(qkv_w, qkvwT, DIM, DIM3);
  k_transpose_cast<<<dim3(DIM * DIM / 256), dim3(256), 0, stream>>>(proj_w, projwT, DIM, DIM);

  k_gemm<0><<<dim3(MP / 128, DIM3 / 128), dim3(256), 0, stream>>>(xb, qkvwT, qkv_b, qkvf);

  k_pool<<<dim3(3 * BHN * NPAD / 4), dim3(256), 0, stream>>>(
      qkvf, pw_q, pw_k, pw_v, nw_q, nb_q, nw_k, nb_k, nw_v, nb_v,
      rel_t, rel_h, rel_w, Qa, Ka, Vt);

  k_attn<<<dim3(BHN * 25), dim3(256), 0, stream>>>(Qa, Ka, Vt, attnO);

  k_gemm<1><<<dim3(MP / 128, DIM / 128), dim3(256), 0, stream>>>(attnO, projwT, proj_b, out);
}

// Round 2
// 391.433 us; speedup vs baseline: 1.7176x; 1.7176x over previous
//
#include <hip/hip_runtime.h>
#include <cstdint>
#include <cstddef>

typedef __attribute__((ext_vector_type(8))) short short8;
typedef __attribute__((ext_vector_type(4))) short short4v;
typedef __attribute__((ext_vector_type(4))) float f32x4;
typedef unsigned short u16;

#define DI __device__ __forceinline__

// ---------------- problem constants ----------------
constexpr int BATCH = 4;
constexpr int HEADS = 12, HD = 64;
constexpr int NTOK = 1569;          // T*H*W + 1
constexpr int NPAD = 1600;          // 25 * 64
constexpr int DIM = 768, DIM3 = 2304;
constexpr int MROWS = BATCH * NTOK; // 6276
constexpr int MP = 6400;            // 50 * 128
constexpr int AUG = 128;            // 64 ch + 8 + 14 + 14 + pad
constexpr int BHN = BATCH * HEADS;  // 48
constexpr float SCALE = 0.125f;
constexpr float LN_EPS = 1e-5f;

// ---------------- helpers ----------------
DI u16 f2bf(float x) {
  union { float f; unsigned u; } v; v.f = x;
  unsigned r = v.u + 0x7FFFu + ((v.u >> 16) & 1u);
  return (u16)(r >> 16);
}
DI float bf2f(u16 h) {
  union { unsigned u; float f; } v; v.u = ((unsigned)h) << 16;
  return v.f;
}

typedef const __attribute__((address_space(1))) unsigned int gu32;
typedef __attribute__((address_space(3))) unsigned int lu32;
DI void gld16(const void* g, void* l) {
  __builtin_amdgcn_global_load_lds((gu32*)g, (lu32*)l, 16, 0, 0);
}

// ---------------- cast kernels ----------------
__global__ __launch_bounds__(256) void k_cast_x(const float* __restrict__ x,
                                                u16* __restrict__ xb) {
  int i = (blockIdx.x * 256 + threadIdx.x) * 4;
  if (i >= MP * DIM) return;
  int row = i / DIM;
  short4v o;
  if (row < MROWS) {
    float4 v = *(const float4*)(x + i);
    o.x = (short)f2bf(v.x); o.y = (short)f2bf(v.y);
    o.z = (short)f2bf(v.z); o.w = (short)f2bf(v.w);
  } else {
    o.x = 0; o.y = 0; o.z = 0; o.w = 0;
  }
  *(short4v*)(xb + i) = o;
}

// dst (NC, K) bf16 = transpose of src (K, NC) f32
__global__ __launch_bounds__(256) void k_transpose_cast(const float* __restrict__ src,
                                                        u16* __restrict__ dst,
                                                        int K, int NC) {
  int i = blockIdx.x * 256 + threadIdx.x;
  if (i >= K * NC) return;
  int n = i / K, k = i - n * K;
  dst[i] = f2bf(src[(size_t)k * NC + n]);
}

// ---------------- GEMM: C(M,N) = A(M,768)*Bt(N,768)^T + bias ----------------
// EPI 0: scatter to qkv ws f32 (t,b,h,n,c).  EPI 1: linear f32 out (proj).
template <int EPI>
__global__ __launch_bounds__(256) void k_gemm(const u16* __restrict__ A,
                                              const u16* __restrict__ Bt,
                                              const float* __restrict__ bias,
                                              float* __restrict__ out) {
  __shared__ __align__(16) u16 sA[128 * 64];
  __shared__ __align__(16) u16 sB[128 * 64];
  const int tid = threadIdx.x;
  const int w = tid >> 6, lane = tid & 63;
  const int g = lane >> 4, lr = lane & 15;
  const int brow = blockIdx.x * 128, bcol = blockIdx.y * 128;
  const int wr = w >> 1, wc = w & 1;

  f32x4 acc[4][4];
#pragma unroll
  for (int m = 0; m < 4; ++m)
#pragma unroll
    for (int n = 0; n < 4; ++n) {
      acc[m][n].x = 0.f; acc[m][n].y = 0.f; acc[m][n].z = 0.f; acc[m][n].w = 0.f;
    }

  for (int kt = 0; kt < 12; ++kt) {
    __syncthreads();
#pragma unroll
    for (int j = 0; j < 4; ++j) {
      int cb = (j * 4 + w) * 64;
      int chunk = cb + lane;
      int row = chunk >> 3, ch = chunk & 7;
      int gch = ch ^ (row & 7);
      gld16(A + (size_t)(brow + row) * DIM + kt * 64 + gch * 8, &sA[cb * 8]);
      gld16(Bt + (size_t)(bcol + row) * DIM + kt * 64 + gch * 8, &sB[cb * 8]);
    }
    __syncthreads();

    short8 af[4][2], bfr[4][2];
#pragma unroll
    for (int m = 0; m < 4; ++m) {
      int row = wr * 64 + m * 16 + lr;
      int sw = row & 7;
#pragma unroll
      for (int ks = 0; ks < 2; ++ks)
        af[m][ks] = *(const short8*)&sA[row * 64 + (((ks * 4 + g) ^ sw) * 8)];
    }
#pragma unroll
    for (int n = 0; n < 4; ++n) {
      int row = wc * 64 + n * 16 + lr;
      int sw = row & 7;
#pragma unroll
      for (int ks = 0; ks < 2; ++ks)
        bfr[n][ks] = *(const short8*)&sB[row * 64 + (((ks * 4 + g) ^ sw) * 8)];
    }
#pragma unroll
    for (int m = 0; m < 4; ++m)
#pragma unroll
      for (int n = 0; n < 4; ++n) {
        acc[m][n] = __builtin_amdgcn_mfma_f32_16x16x32_bf16(af[m][0], bfr[n][0], acc[m][n], 0, 0, 0);
        acc[m][n] = __builtin_amdgcn_mfma_f32_16x16x32_bf16(af[m][1], bfr[n][1], acc[m][n], 0, 0, 0);
      }
  }

#pragma unroll
  for (int m = 0; m < 4; ++m)
#pragma unroll
    for (int n = 0; n < 4; ++n) {
      int gj = bcol + wc * 64 + n * 16 + lr;
      float bv = bias[gj];
#pragma unroll
      for (int r = 0; r < 4; ++r) {
        int gm = brow + wr * 64 + m * 16 + g * 4 + r;
        if (gm >= MROWS) continue;
        float v = acc[m][n][r] + bv;
        if (EPI == 0) {
          int t = gj >= 1536 ? 2 : (gj >= 768 ? 1 : 0);
          int rem = gj - t * 768;
          int h = rem >> 6, c = rem & 63;
          int b = gm >= 3 * NTOK ? 3 : (gm >= 2 * NTOK ? 2 : (gm >= NTOK ? 1 : 0));
          int nt = gm - b * NTOK;
          out[(((size_t)(t * BATCH + b) * HEADS + h) * NPAD + nt) * HD + c] = v;
        } else {
          out[(size_t)gm * DIM + gj] = v;
        }
      }
    }
}

// ---------------- pool (depthwise conv3d) + LN + rel rows + aug writes ----------------
// Wave = one (tau, bh, t, h) row; slides 3x3x3 window along w (14 tokens).
// Weights live in 27 regs per lane, window in 27 regs (9 x 3 columns).
DI float ldsrc(const float* __restrict__ src, int tt, int h2, int w2, int lane) {
  if ((unsigned)tt >= 8u || (unsigned)h2 >= 14u || (unsigned)w2 >= 14u) return 0.f;
  return src[(size_t)(1 + (tt * 14 + h2) * 14 + w2) * HD + lane];
}

__global__ __launch_bounds__(256) void k_pool(
    const float* __restrict__ qkv,
    const float* __restrict__ pw_q, const float* __restrict__ pw_k, const float* __restrict__ pw_v,
    const float* __restrict__ nw_q, const float* __restrict__ nb_q,
    const float* __restrict__ nw_k, const float* __restrict__ nb_k,
    const float* __restrict__ nw_v, const float* __restrict__ nb_v,
    const float* __restrict__ rel_t, const float* __restrict__ rel_h, const float* __restrict__ rel_w,
    u16* __restrict__ Qa, u16* __restrict__ Ka, u16* __restrict__ Vt) {
  __shared__ __align__(16) float sQv[4][64];
  const int wv = threadIdx.x >> 6, lane = threadIdx.x & 63;
  const int unit = blockIdx.x % 29;
  const int taubh = blockIdx.x / 29;
  const int tau = taubh / BHN, bh = taubh % BHN;
  const float* src = qkv + ((size_t)tau * BHN + bh) * ((size_t)NPAD * HD);
  const float* nw = tau == 0 ? nw_q : tau == 1 ? nw_k : nw_v;
  const float* nb = tau == 0 ? nb_q : tau == 1 ? nb_k : nb_v;

  if (unit == 28) {
    if (wv == 0) {
      // CLS token (n = 0): identity copy + LN
      float val = src[lane];
      float s = val, sq = val * val;
#pragma unroll
      for (int off = 1; off < 64; off <<= 1) { s += __shfl_xor(s, off); sq += __shfl_xor(sq, off); }
      float mean = s * (1.f / 64.f);
      float var = sq * (1.f / 64.f) - mean * mean;
      float ln = (val - mean) * rsqrtf(var + LN_EPS) * nw[lane] + nb[lane];
      size_t base = (size_t)bh * NPAD * AUG;
      if (tau == 0)      { Qa[base + lane] = f2bf(ln * SCALE); Qa[base + 64 + lane] = 0; }
      else if (tau == 1) { Ka[base + lane] = f2bf(ln);         Ka[base + 64 + lane] = 0; }
      else               { Vt[((size_t)bh * HD + lane) * NPAD] = f2bf(ln); }
    } else {
      // pad rows 1569..1599 -> zero
      for (int n = 1569 + (wv - 1); n < NPAD; n += 3) {
        if (tau == 0) {
          size_t base = (size_t)(bh * NPAD + n) * AUG;
          Qa[base + lane] = 0; Qa[base + 64 + lane] = 0;
        } else if (tau == 1) {
          size_t base = (size_t)(bh * NPAD + n) * AUG;
          Ka[base + lane] = 0; Ka[base + 64 + lane] = 0;
        } else {
          Vt[((size_t)bh * HD + lane) * NPAD + n] = 0;
        }
      }
    }
    return;
  }

  const int th = unit * 4 + wv;          // 0..111
  const int t = th / 14, hh = th % 14;

  float wt[27];
  {
    const float* wp = (tau == 0 ? pw_q : tau == 1 ? pw_k : pw_v) + lane * 27;
#pragma unroll
    for (int j = 0; j < 27; ++j) wt[j] = wp[j];
  }

  float win[9][3];
#pragma unroll
  for (int dt = 0; dt < 3; ++dt)
#pragma unroll
    for (int dh = 0; dh < 3; ++dh) {
      win[dt * 3 + dh][0] = 0.f;
      win[dt * 3 + dh][1] = ldsrc(src, t + dt - 1, hh + dh - 1, 0, lane);
      win[dt * 3 + dh][2] = ldsrc(src, t + dt - 1, hh + dh - 1, 1, lane);
    }

#pragma unroll
  for (int ww = 0; ww < 14; ++ww) {
    float a = 0.f;
#pragma unroll
    for (int i = 0; i < 9; ++i)
      a += win[i][0] * wt[i * 3 + 0] + win[i][1] * wt[i * 3 + 1] + win[i][2] * wt[i * 3 + 2];

    // LayerNorm over 64 channels
    float s = a, sq = a * a;
#pragma unroll
    for (int off = 1; off < 64; off <<= 1) { s += __shfl_xor(s, off); sq += __shfl_xor(sq, off); }
    float mean = s * (1.f / 64.f);
    float var = sq * (1.f / 64.f) - mean * mean;
    float ln = (a - mean) * rsqrtf(var + LN_EPS) * nw[lane] + nb[lane];

    const int n = 1 + (t * 14 + hh) * 14 + ww;
    if (tau == 0) {
      sQv[wv][lane] = ln;
      float dot = 0.f;
      if (lane < 36) {
        const float* Mrow = lane < 8  ? rel_t + (size_t)(t - lane + 7) * HD
                          : lane < 22 ? rel_h + (size_t)(hh - (lane - 8) + 13) * HD
                                      : rel_w + (size_t)(ww - (lane - 22) + 13) * HD;
#pragma unroll
        for (int cc = 0; cc < 16; ++cc) {
          float4 qv = *(const float4*)&sQv[wv][cc * 4];
          float4 mv = *(const float4*)&Mrow[cc * 4];
          dot += qv.x * mv.x + qv.y * mv.y + qv.z * mv.z + qv.w * mv.w;
        }
      }
      size_t base = (size_t)(bh * NPAD + n) * AUG;
      Qa[base + lane] = f2bf(ln * SCALE);
      Qa[base + 64 + lane] = lane < 36 ? f2bf(dot) : (u16)0;
    } else if (tau == 1) {
      size_t base = (size_t)(bh * NPAD + n) * AUG;
      Ka[base + lane] = f2bf(ln);
      u16 e = 0;
      if (lane == t || lane == 8 + hh || lane == 22 + ww) e = 0x3F80;  // bf16 1.0
      Ka[base + 64 + lane] = e;
    } else {
      Vt[((size_t)bh * HD + lane) * NPAD + n] = f2bf(ln);
    }

    // slide window: shift left, load column ww+2
#pragma unroll
    for (int i = 0; i < 9; ++i) { win[i][0] = win[i][1]; win[i][1] = win[i][2]; }
#pragma unroll
    for (int dt = 0; dt < 3; ++dt)
#pragma unroll
      for (int dh = 0; dh < 3; ++dh)
        win[dt * 3 + dh][2] = ldsrc(src, t + dt - 1, hh + dh - 1, ww + 2, lane);
  }
}

// ---------------- fused flash attention ----------------
__global__ __launch_bounds__(256) void k_attn(const u16* __restrict__ Qa,
                                              const u16* __restrict__ Ka,
                                              const u16* __restrict__ Vt,
                                              u16* __restrict__ outA) {
  __shared__ __align__(16) u16 sK[64 * 128];   // K_aug tile, chunk-swizzled
  __shared__ __align__(16) u16 sV[64 * 64];    // V^T tile [c][key], chunk-swizzled
  __shared__ __align__(16) u16 sP[4][16 * 72]; // per-wave P, padded stride 72
  const int tid = threadIdx.x, w = tid >> 6, lane = tid & 63;
  const int g = lane >> 4, lr = lane & 15;
  const int bh = blockIdx.x / 25, qt = blockIdx.x % 25;
  const int b = bh / HEADS, h = bh - b * HEADS;
  const int q0 = qt * 64 + w * 16;

  short8 aq[4];
  {
    const u16* qrow = Qa + ((size_t)bh * NPAD + q0 + lr) * AUG;
#pragma unroll
    for (int ks = 0; ks < 4; ++ks) aq[ks] = *(const short8*)(qrow + ks * 32 + g * 8);
  }

  f32x4 O[4];
#pragma unroll
  for (int c4 = 0; c4 < 4; ++c4) { O[c4].x = 0.f; O[c4].y = 0.f; O[c4].z = 0.f; O[c4].w = 0.f; }
  float mrun[4], lrun[4];
#pragma unroll
  for (int r = 0; r < 4; ++r) { mrun[r] = -1e30f; lrun[r] = 0.f; }

  for (int kb = 0; kb < 25; ++kb) {
    const u16* Kb = Ka + ((size_t)bh * NPAD + kb * 64) * AUG;
#pragma unroll
    for (int j = 0; j < 4; ++j) {
      int cb = (j * 4 + w) * 64;
      int chunk = cb + lane;
      int row = chunk >> 4, ch = chunk & 15;
      int gch = ch ^ (row & 7);
      gld16(Kb + (size_t)row * AUG + gch * 8, &sK[cb * 8]);
    }
    const u16* Vb = Vt + (size_t)bh * HD * NPAD + kb * 64;
#pragma unroll
    for (int j = 0; j < 2; ++j) {
      int cb = (j * 4 + w) * 64;
      int chunk = cb + lane;
      int row = chunk >> 3, ch = chunk & 7;
      int gch = ch ^ (row & 7);
      gld16(Vb + (size_t)row * NPAD + gch * 8, &sV[cb * 8]);
    }
    __syncthreads();

    // S = Q_aug * K_aug^T  (D layout: row q = g*4+r, col key = lr)
    f32x4 sacc[4];
#pragma unroll
    for (int ct = 0; ct < 4; ++ct) {
      f32x4 a; a.x = 0.f; a.y = 0.f; a.z = 0.f; a.w = 0.f;
      int row = ct * 16 + lr;
      int sw = row & 7;
#pragma unroll
      for (int ks = 0; ks < 4; ++ks) {
        short8 bk = *(const short8*)&sK[row * 128 + (((ks * 4 + g) ^ sw) * 8)];
        a = __builtin_amdgcn_mfma_f32_16x16x32_bf16(aq[ks], bk, a, 0, 0, 0);
      }
      sacc[ct] = a;
    }
    // mask invalid keys
    int key0 = kb * 64 + lr;
#pragma unroll
    for (int ct = 0; ct < 4; ++ct)
      if (key0 + ct * 16 >= NTOK) {
        sacc[ct].x = -1e30f; sacc[ct].y = -1e30f; sacc[ct].z = -1e30f; sacc[ct].w = -1e30f;
      }
    // online softmax per q-row r
#pragma unroll
    for (int r = 0; r < 4; ++r) {
      float mx = fmaxf(fmaxf(sacc[0][r], sacc[1][r]), fmaxf(sacc[2][r], sacc[3][r]));
#pragma unroll
      for (int off = 1; off < 16; off <<= 1) mx = fmaxf(mx, __shfl_xor(mx, off));
      float nm = fmaxf(mrun[r], mx);
      float sc = __expf(mrun[r] - nm);
      mrun[r] = nm;
      float ps = 0.f;
#pragma unroll
      for (int ct = 0; ct < 4; ++ct) {
        float p = __expf(sacc[ct][r] - nm);
        sacc[ct][r] = p;
        ps += p;
      }
#pragma unroll
      for (int off = 1; off < 16; off <<= 1) ps += __shfl_xor(ps, off);
      lrun[r] = lrun[r] * sc + ps;
#pragma unroll
      for (int c4 = 0; c4 < 4; ++c4) O[c4][r] *= sc;
      int qo = g * 4 + r;
#pragma unroll
      for (int ct = 0; ct < 4; ++ct)
        sP[w][qo * 72 + ct * 16 + lr] = f2bf(sacc[ct][r]);
    }
    // O += P * V
#pragma unroll
    for (int kk = 0; kk < 2; ++kk) {
      short8 ap = *(const short8*)&sP[w][lr * 72 + kk * 32 + g * 8];
#pragma unroll
      for (int c4 = 0; c4 < 4; ++c4) {
        int row = c4 * 16 + lr;
        int sw = row & 7;
        short8 bv = *(const short8*)&sV[row * 64 + (((kk * 4 + g) ^ sw) * 8)];
        O[c4] = __builtin_amdgcn_mfma_f32_16x16x32_bf16(ap, bv, O[c4], 0, 0, 0);
      }
    }
    __syncthreads();
  }

  // epilogue: normalize, residual (+pooled q), store bf16
#pragma unroll
  for (int r = 0; r < 4; ++r) {
    int qg = q0 + g * 4 + r;
    if (qg >= NTOK) continue;
    float inv = 1.f / lrun[r];
#pragma unroll
    for (int c4 = 0; c4 < 4; ++c4) {
      float v = O[c4][r] * inv;
      int c = c4 * 16 + lr;
      if (qg >= 1) v += 8.f * bf2f(Qa[((size_t)bh * NPAD + qg) * AUG + c]);
      outA[((size_t)(b * NTOK + qg)) * DIM + h * HD + c] = f2bf(v);
    }
  }
}

// ---------------- launch ----------------
extern "C" void kernel_launch(void* const* d_in, const int* in_sizes, int n_in,
                              void* d_out, int out_size, void* d_ws, size_t ws_size,
                              hipStream_t stream) {
  (void)in_sizes; (void)n_in; (void)out_size; (void)ws_size;
  const float* x      = (const float*)d_in[0];
  const float* qkv_w  = (const float*)d_in[1];
  const float* qkv_b  = (const float*)d_in[2];
  const float* proj_w = (const float*)d_in[3];
  const float* proj_b = (const float*)d_in[4];
  const float* pw_q   = (const float*)d_in[5];
  const float* pw_k   = (const float*)d_in[6];
  const float* pw_v   = (const float*)d_in[7];
  const float* nw_q   = (const float*)d_in[8];
  const float* nb_q   = (const float*)d_in[9];
  const float* nw_k   = (const float*)d_in[10];
  const float* nb_k   = (const float*)d_in[11];
  const float* nw_v   = (const float*)d_in[12];
  const float* nb_v   = (const float*)d_in[13];
  const float* rel_t  = (const float*)d_in[14];
  const float* rel_h  = (const float*)d_in[15];
  const float* rel_w  = (const float*)d_in[16];
  float* out = (float*)d_out;

  char* ws = (char*)d_ws;
  size_t off = 0;
  auto alloc = [&](size_t bytes) -> void* {
    off = (off + 511) & ~(size_t)511;
    void* p = ws + off;
    off += bytes;
    return p;
  };
  u16*   xb     = (u16*)alloc((size_t)MP * DIM * 2);
  u16*   qkvwT  = (u16*)alloc((size_t)DIM3 * DIM * 2);
  u16*   projwT = (u16*)alloc((size_t)DIM * DIM * 2);
  float* qkvf   = (float*)alloc((size_t)3 * BHN * NPAD * HD * 4);
  u16*   Qa     = (u16*)alloc((size_t)BHN * NPAD * AUG * 2);
  u16*   Ka     = (u16*)alloc((size_t)BHN * NPAD * AUG * 2);
  u16*   Vt     = (u16*)alloc((size_t)BHN * HD * NPAD * 2);
  u16*   attnO  = (u16*)alloc((size_t)MP * DIM * 2);

  k_cast_x<<<dim3(MP * DIM / 1024), dim3(256), 0, stream>>>(x, xb);
  k_transpose_cast<<<dim3(DIM3 * DIM / 256), dim3(256), 0, stream>>>(qkv_w, qkvwT, DIM, DIM3);
  k_transpose_cast<<<dim3(DIM * DIM / 256), dim3(256), 0, stream>>>(proj_w, projwT, DIM, DIM);

  k_gemm<0><<<dim3(MP / 128, DIM3 / 128), dim3(256), 0, stream>>>(xb, qkvwT, qkv_b, qkvf);

  k_pool<<<dim3(3 * BHN * 29), dim3(256), 0, stream>>>(
      qkvf, pw_q, pw_k, pw_v, nw_q, nb_q, nw_k, nb_k, nw_v, nb_v,
      rel_t, rel_h, rel_w, Qa, Ka, Vt);

  k_attn<<<dim3(BHN * 25), dim3(256), 0, stream>>>(Qa, Ka, Vt, attnO);

  k_gemm<1><<<dim3(MP / 128, DIM / 128), dim3(256), 0, stream>>>(attnO, projwT, proj_b, out);
}

// Round 3
// 319.956 us; speedup vs baseline: 2.1013x; 1.2234x over previous
//
#include <hip/hip_runtime.h>
#include <cstdint>
#include <cstddef>

typedef __attribute__((ext_vector_type(8))) short short8;
typedef __attribute__((ext_vector_type(4))) short short4v;
typedef __attribute__((ext_vector_type(4))) float f32x4;
typedef unsigned short u16;

#define DI __device__ __forceinline__

// ---------------- problem constants ----------------
constexpr int BATCH = 4;
constexpr int HEADS = 12, HD = 64;
constexpr int NTOK = 1569;          // T*H*W + 1
constexpr int NPAD = 1600;          // 25 * 64
constexpr int DIM = 768, DIM3 = 2304;
constexpr int MROWS = BATCH * NTOK; // 6276
constexpr int MP = 6400;            // 50 * 128
constexpr int AUG = 128;            // 64 ch + 8 + 14 + 14 + pad
constexpr int BHN = BATCH * HEADS;  // 48
constexpr float SCALE = 0.125f;
constexpr float LN_EPS = 1e-5f;

// ---------------- helpers ----------------
DI u16 f2bf(float x) {
  union { float f; unsigned u; } v; v.f = x;
  unsigned r = v.u + 0x7FFFu + ((v.u >> 16) & 1u);
  return (u16)(r >> 16);
}
DI float bf2f(u16 h) {
  union { unsigned u; float f; } v; v.u = ((unsigned)h) << 16;
  return v.f;
}

typedef const __attribute__((address_space(1))) unsigned int gu32;
typedef __attribute__((address_space(3))) unsigned int lu32;
DI void gld16(const void* g, void* l) {
  __builtin_amdgcn_global_load_lds((gu32*)g, (lu32*)l, 16, 0, 0);
}

// ---------------- cast kernels ----------------
__global__ __launch_bounds__(256) void k_cast_x(const float* __restrict__ x,
                                                u16* __restrict__ xb) {
  int i = (blockIdx.x * 256 + threadIdx.x) * 4;
  if (i >= MP * DIM) return;
  int row = i / DIM;
  short4v o;
  if (row < MROWS) {
    float4 v = *(const float4*)(x + i);
    o.x = (short)f2bf(v.x); o.y = (short)f2bf(v.y);
    o.z = (short)f2bf(v.z); o.w = (short)f2bf(v.w);
  } else {
    o.x = 0; o.y = 0; o.z = 0; o.w = 0;
  }
  *(short4v*)(xb + i) = o;
}

// dst (NC, K) bf16 = transpose of src (K, NC) f32 — LDS 32x32 tile transpose
__global__ __launch_bounds__(256) void k_transpose_cast(const float* __restrict__ src,
                                                        u16* __restrict__ dst,
                                                        int K, int NC) {
  __shared__ float tile[32][33];
  const int ntiles = NC >> 5;
  const int bx = blockIdx.x % ntiles;  // n-tile
  const int by = blockIdx.x / ntiles;  // k-tile
  const int tx = threadIdx.x & 31, ty = threadIdx.x >> 5;
  const int n0 = bx * 32, k0 = by * 32;
#pragma unroll
  for (int r = 0; r < 32; r += 8)
    tile[ty + r][tx] = src[(size_t)(k0 + ty + r) * NC + n0 + tx];
  __syncthreads();
#pragma unroll
  for (int r = 0; r < 32; r += 8)
    dst[(size_t)(n0 + ty + r) * K + k0 + tx] = f2bf(tile[tx][ty + r]);
}

// ---------------- GEMM: C(M,N) = A(M,768)*Bt(N,768)^T + bias ----------------
// EPI 0: scatter to qkv ws f32 (t,b,h,n,c).  EPI 1: linear f32 out (proj).
template <int EPI>
__global__ __launch_bounds__(256) void k_gemm(const u16* __restrict__ A,
                                              const u16* __restrict__ Bt,
                                              const float* __restrict__ bias,
                                              float* __restrict__ out) {
  __shared__ __align__(16) u16 sA[128 * 64];
  __shared__ __align__(16) u16 sB[128 * 64];
  const int tid = threadIdx.x;
  const int w = tid >> 6, lane = tid & 63;
  const int g = lane >> 4, lr = lane & 15;
  const int brow = blockIdx.x * 128, bcol = blockIdx.y * 128;
  const int wr = w >> 1, wc = w & 1;

  f32x4 acc[4][4];
#pragma unroll
  for (int m = 0; m < 4; ++m)
#pragma unroll
    for (int n = 0; n < 4; ++n) {
      acc[m][n].x = 0.f; acc[m][n].y = 0.f; acc[m][n].z = 0.f; acc[m][n].w = 0.f;
    }

  for (int kt = 0; kt < 12; ++kt) {
    __syncthreads();
#pragma unroll
    for (int j = 0; j < 4; ++j) {
      int cb = (j * 4 + w) * 64;
      int chunk = cb + lane;
      int row = chunk >> 3, ch = chunk & 7;
      int gch = ch ^ (row & 7);
      gld16(A + (size_t)(brow + row) * DIM + kt * 64 + gch * 8, &sA[cb * 8]);
      gld16(Bt + (size_t)(bcol + row) * DIM + kt * 64 + gch * 8, &sB[cb * 8]);
    }
    __syncthreads();

    short8 af[4][2], bfr[4][2];
#pragma unroll
    for (int m = 0; m < 4; ++m) {
      int row = wr * 64 + m * 16 + lr;
      int sw = row & 7;
#pragma unroll
      for (int ks = 0; ks < 2; ++ks)
        af[m][ks] = *(const short8*)&sA[row * 64 + (((ks * 4 + g) ^ sw) * 8)];
    }
#pragma unroll
    for (int n = 0; n < 4; ++n) {
      int row = wc * 64 + n * 16 + lr;
      int sw = row & 7;
#pragma unroll
      for (int ks = 0; ks < 2; ++ks)
        bfr[n][ks] = *(const short8*)&sB[row * 64 + (((ks * 4 + g) ^ sw) * 8)];
    }
#pragma unroll
    for (int m = 0; m < 4; ++m)
#pragma unroll
      for (int n = 0; n < 4; ++n) {
        acc[m][n] = __builtin_amdgcn_mfma_f32_16x16x32_bf16(af[m][0], bfr[n][0], acc[m][n], 0, 0, 0);
        acc[m][n] = __builtin_amdgcn_mfma_f32_16x16x32_bf16(af[m][1], bfr[n][1], acc[m][n], 0, 0, 0);
      }
  }

#pragma unroll
  for (int m = 0; m < 4; ++m)
#pragma unroll
    for (int n = 0; n < 4; ++n) {
      int gj = bcol + wc * 64 + n * 16 + lr;
      float bv = bias[gj];
#pragma unroll
      for (int r = 0; r < 4; ++r) {
        int gm = brow + wr * 64 + m * 16 + g * 4 + r;
        if (gm >= MROWS) continue;
        float v = acc[m][n][r] + bv;
        if (EPI == 0) {
          int t = gj >= 1536 ? 2 : (gj >= 768 ? 1 : 0);
          int rem = gj - t * 768;
          int h = rem >> 6, c = rem & 63;
          int b = gm >= 3 * NTOK ? 3 : (gm >= 2 * NTOK ? 2 : (gm >= NTOK ? 1 : 0));
          int nt = gm - b * NTOK;
          out[(((size_t)(t * BATCH + b) * HEADS + h) * NPAD + nt) * HD + c] = v;
        } else {
          out[(size_t)gm * DIM + gj] = v;
        }
      }
    }
}

// ---------------- pool (depthwise conv3d) + LN + aug writes ----------------
// Wave = one (tau, bh, t, h) row; slides 3x3x3 window along w (14 tokens).
DI float ldsrc(const float* __restrict__ src, int tt, int h2, int w2, int lane) {
  if ((unsigned)tt >= 8u || (unsigned)h2 >= 14u || (unsigned)w2 >= 14u) return 0.f;
  return src[(size_t)(1 + (tt * 14 + h2) * 14 + w2) * HD + lane];
}

__global__ __launch_bounds__(256, 4) void k_pool(
    const float* __restrict__ qkv,
    const float* __restrict__ pw_q, const float* __restrict__ pw_k, const float* __restrict__ pw_v,
    const float* __restrict__ nw_q, const float* __restrict__ nb_q,
    const float* __restrict__ nw_k, const float* __restrict__ nb_k,
    const float* __restrict__ nw_v, const float* __restrict__ nb_v,
    u16* __restrict__ Qa, u16* __restrict__ Ka, u16* __restrict__ Vt) {
  const int wv = threadIdx.x >> 6, lane = threadIdx.x & 63;
  const int unit = blockIdx.x % 29;
  const int taubh = blockIdx.x / 29;
  const int tau = taubh / BHN, bh = taubh % BHN;
  const float* src = qkv + ((size_t)tau * BHN + bh) * ((size_t)NPAD * HD);
  const float* nw = tau == 0 ? nw_q : tau == 1 ? nw_k : nw_v;
  const float* nb = tau == 0 ? nb_q : tau == 1 ? nb_k : nb_v;

  if (unit == 28) {
    if (wv == 0) {
      // CLS token (n = 0): identity + LN
      float val = src[lane];
      float s = val, sq = val * val;
#pragma unroll
      for (int off = 1; off < 64; off <<= 1) { s += __shfl_xor(s, off); sq += __shfl_xor(sq, off); }
      float mean = s * (1.f / 64.f);
      float var = sq * (1.f / 64.f) - mean * mean;
      float ln = (val - mean) * rsqrtf(var + LN_EPS) * nw[lane] + nb[lane];
      size_t base = (size_t)bh * NPAD * AUG;
      if (tau == 0)      { Qa[base + lane] = f2bf(ln * SCALE); Qa[base + 64 + lane] = 0; }
      else if (tau == 1) { Ka[base + lane] = f2bf(ln);         Ka[base + 64 + lane] = 0; }
      else               { Vt[((size_t)bh * HD + lane) * NPAD] = f2bf(ln); }
    } else {
      // pad rows 1569..1599 -> zero
      for (int n = 1569 + (wv - 1); n < NPAD; n += 3) {
        if (tau == 0) {
          size_t base = (size_t)(bh * NPAD + n) * AUG;
          Qa[base + lane] = 0; Qa[base + 64 + lane] = 0;
        } else if (tau == 1) {
          size_t base = (size_t)(bh * NPAD + n) * AUG;
          Ka[base + lane] = 0; Ka[base + 64 + lane] = 0;
        } else {
          Vt[((size_t)bh * HD + lane) * NPAD + n] = 0;
        }
      }
    }
    return;
  }

  const int th = unit * 4 + wv;          // 0..111
  const int t = th / 14, hh = th % 14;

  float wt[27];
  {
    const float* wp = (tau == 0 ? pw_q : tau == 1 ? pw_k : pw_v) + lane * 27;
#pragma unroll
    for (int j = 0; j < 27; ++j) wt[j] = wp[j];
  }

  float win[9][3];
#pragma unroll
  for (int dt = 0; dt < 3; ++dt)
#pragma unroll
    for (int dh = 0; dh < 3; ++dh) {
      win[dt * 3 + dh][0] = 0.f;
      win[dt * 3 + dh][1] = ldsrc(src, t + dt - 1, hh + dh - 1, 0, lane);
      win[dt * 3 + dh][2] = ldsrc(src, t + dt - 1, hh + dh - 1, 1, lane);
    }

#pragma unroll
  for (int ww = 0; ww < 14; ++ww) {
    // prefetch next column first (used next iteration -> load/use distance = conv+LN)
    float nxt[9];
#pragma unroll
    for (int dt = 0; dt < 3; ++dt)
#pragma unroll
      for (int dh = 0; dh < 3; ++dh)
        nxt[dt * 3 + dh] = ldsrc(src, t + dt - 1, hh + dh - 1, ww + 2, lane);

    float a = 0.f;
#pragma unroll
    for (int i = 0; i < 9; ++i)
      a += win[i][0] * wt[i * 3 + 0] + win[i][1] * wt[i * 3 + 1] + win[i][2] * wt[i * 3 + 2];

    // LayerNorm over 64 channels
    float s = a, sq = a * a;
#pragma unroll
    for (int off = 1; off < 64; off <<= 1) { s += __shfl_xor(s, off); sq += __shfl_xor(sq, off); }
    float mean = s * (1.f / 64.f);
    float var = sq * (1.f / 64.f) - mean * mean;
    float ln = (a - mean) * rsqrtf(var + LN_EPS) * nw[lane] + nb[lane];

    const int n = 1 + (t * 14 + hh) * 14 + ww;
    if (tau == 0) {
      size_t base = (size_t)(bh * NPAD + n) * AUG;
      Qa[base + lane] = f2bf(ln * SCALE);
      Qa[base + 64 + lane] = 0;  // k_rel fills lanes 64..99
    } else if (tau == 1) {
      size_t base = (size_t)(bh * NPAD + n) * AUG;
      Ka[base + lane] = f2bf(ln);
      u16 e = 0;
      if (lane == t || lane == 8 + hh || lane == 22 + ww) e = 0x3F80;  // bf16 1.0
      Ka[base + 64 + lane] = e;
    } else {
      Vt[((size_t)bh * HD + lane) * NPAD + n] = f2bf(ln);
    }

    // slide window
#pragma unroll
    for (int i = 0; i < 9; ++i) { win[i][0] = win[i][1]; win[i][1] = win[i][2]; win[i][2] = nxt[i]; }
  }
}

// ---------------- rel-pos dot table via MFMA ----------------
// P[q][j] = (q_ln) . RelAll[j]  (RelAll = concat(rel_t 15, rel_h 27, rel_w 27), x8
// to undo the SCALE folded into Qa).  Scatter P into Qa aug lanes by coords.
__global__ __launch_bounds__(256) void k_rel(const float* __restrict__ rel_t,
                                             const float* __restrict__ rel_h,
                                             const float* __restrict__ rel_w,
                                             u16* __restrict__ Qa) {
  __shared__ __align__(16) u16 sR[80 * 72];  // [j][c], pad 72 to break bank conflicts
  const int tid = threadIdx.x, w = tid >> 6, lane = tid & 63;
  const int g = lane >> 4, lr = lane & 15;
  const int bh = blockIdx.x / 25, qt = blockIdx.x % 25;

  for (int idx = tid; idx < 80 * 64; idx += 256) {
    int j = idx >> 6, c = idx & 63;
    float v = 0.f;
    if (j < 15)      v = rel_t[j * HD + c];
    else if (j < 42) v = rel_h[(j - 15) * HD + c];
    else if (j < 69) v = rel_w[(j - 42) * HD + c];
    sR[j * 72 + c] = f2bf(v * 8.f);
  }
  __syncthreads();

  const int q0 = qt * 64 + w * 16;
  short8 aq[2];
  {
    const u16* qrow = Qa + ((size_t)bh * NPAD + q0 + lr) * AUG;
    aq[0] = *(const short8*)(qrow + g * 8);
    aq[1] = *(const short8*)(qrow + 32 + g * 8);
  }

  f32x4 acc[5];
#pragma unroll
  for (int jt = 0; jt < 5; ++jt) {
    f32x4 a; a.x = 0.f; a.y = 0.f; a.z = 0.f; a.w = 0.f;
    int row = jt * 16 + lr;
    short8 b0 = *(const short8*)&sR[row * 72 + g * 8];
    short8 b1 = *(const short8*)&sR[row * 72 + (4 + g) * 8];
    a = __builtin_amdgcn_mfma_f32_16x16x32_bf16(aq[0], b0, a, 0, 0, 0);
    a = __builtin_amdgcn_mfma_f32_16x16x32_bf16(aq[1], b1, a, 0, 0, 0);
    acc[jt] = a;
  }

#pragma unroll
  for (int jt = 0; jt < 5; ++jt) {
    int j = jt * 16 + lr;
#pragma unroll
    for (int r = 0; r < 4; ++r) {
      int gq = q0 + g * 4 + r;
      if (gq < 1 || gq >= NTOK) continue;
      int p = gq - 1;
      int t = p / 196, pr = p - t * 196;
      int hh = pr / 14, ww = pr - hh * 14;
      int it = t + 7 - j;
      int ih = hh + 28 - j;
      int iw = ww + 55 - j;
      int i = -1;
      if ((unsigned)it < 8u) i = it;
      else if ((unsigned)ih < 14u) i = 8 + ih;
      else if ((unsigned)iw < 14u) i = 22 + iw;
      if (i >= 0)
        Qa[((size_t)bh * NPAD + gq) * AUG + 64 + i] = f2bf(acc[jt][r]);
    }
  }
}

// ---------------- fused flash attention ----------------
__global__ __launch_bounds__(256) void k_attn(const u16* __restrict__ Qa,
                                              const u16* __restrict__ Ka,
                                              const u16* __restrict__ Vt,
                                              u16* __restrict__ outA) {
  __shared__ __align__(16) u16 sK[64 * 128];   // K_aug tile, chunk-swizzled
  __shared__ __align__(16) u16 sV[64 * 64];    // V^T tile [c][key], chunk-swizzled
  __shared__ __align__(16) u16 sP[4][16 * 72]; // per-wave P, padded stride 72
  const int tid = threadIdx.x, w = tid >> 6, lane = tid & 63;
  const int g = lane >> 4, lr = lane & 15;
  const int bh = blockIdx.x / 25, qt = blockIdx.x % 25;
  const int b = bh / HEADS, h = bh - b * HEADS;
  const int q0 = qt * 64 + w * 16;

  short8 aq[4];
  {
    const u16* qrow = Qa + ((size_t)bh * NPAD + q0 + lr) * AUG;
#pragma unroll
    for (int ks = 0; ks < 4; ++ks) aq[ks] = *(const short8*)(qrow + ks * 32 + g * 8);
  }

  f32x4 O[4];
#pragma unroll
  for (int c4 = 0; c4 < 4; ++c4) { O[c4].x = 0.f; O[c4].y = 0.f; O[c4].z = 0.f; O[c4].w = 0.f; }
  float mrun[4], lrun[4];
#pragma unroll
  for (int r = 0; r < 4; ++r) { mrun[r] = -1e30f; lrun[r] = 0.f; }

  for (int kb = 0; kb < 25; ++kb) {
    const u16* Kb = Ka + ((size_t)bh * NPAD + kb * 64) * AUG;
#pragma unroll
    for (int j = 0; j < 4; ++j) {
      int cb = (j * 4 + w) * 64;
      int chunk = cb + lane;
      int row = chunk >> 4, ch = chunk & 15;
      int gch = ch ^ (row & 7);
      gld16(Kb + (size_t)row * AUG + gch * 8, &sK[cb * 8]);
    }
    const u16* Vb = Vt + (size_t)bh * HD * NPAD + kb * 64;
#pragma unroll
    for (int j = 0; j < 2; ++j) {
      int cb = (j * 4 + w) * 64;
      int chunk = cb + lane;
      int row = chunk >> 3, ch = chunk & 7;
      int gch = ch ^ (row & 7);
      gld16(Vb + (size_t)row * NPAD + gch * 8, &sV[cb * 8]);
    }
    __syncthreads();

    // S = Q_aug * K_aug^T  (D layout: row q = g*4+r, col key = lr)
    f32x4 sacc[4];
#pragma unroll
    for (int ct = 0; ct < 4; ++ct) {
      f32x4 a; a.x = 0.f; a.y = 0.f; a.z = 0.f; a.w = 0.f;
      int row = ct * 16 + lr;
      int sw = row & 7;
#pragma unroll
      for (int ks = 0; ks < 4; ++ks) {
        short8 bk = *(const short8*)&sK[row * 128 + (((ks * 4 + g) ^ sw) * 8)];
        a = __builtin_amdgcn_mfma_f32_16x16x32_bf16(aq[ks], bk, a, 0, 0, 0);
      }
      sacc[ct] = a;
    }
    // mask invalid keys
    int key0 = kb * 64 + lr;
#pragma unroll
    for (int ct = 0; ct < 4; ++ct)
      if (key0 + ct * 16 >= NTOK) {
        sacc[ct].x = -1e30f; sacc[ct].y = -1e30f; sacc[ct].z = -1e30f; sacc[ct].w = -1e30f;
      }
    // online softmax per q-row r
#pragma unroll
    for (int r = 0; r < 4; ++r) {
      float mx = fmaxf(fmaxf(sacc[0][r], sacc[1][r]), fmaxf(sacc[2][r], sacc[3][r]));
#pragma unroll
      for (int off = 1; off < 16; off <<= 1) mx = fmaxf(mx, __shfl_xor(mx, off));
      float nm = fmaxf(mrun[r], mx);
      float sc = __expf(mrun[r] - nm);
      mrun[r] = nm;
      float ps = 0.f;
#pragma unroll
      for (int ct = 0; ct < 4; ++ct) {
        float p = __expf(sacc[ct][r] - nm);
        sacc[ct][r] = p;
        ps += p;
      }
#pragma unroll
      for (int off = 1; off < 16; off <<= 1) ps += __shfl_xor(ps, off);
      lrun[r] = lrun[r] * sc + ps;
#pragma unroll
      for (int c4 = 0; c4 < 4; ++c4) O[c4][r] *= sc;
      int qo = g * 4 + r;
#pragma unroll
      for (int ct = 0; ct < 4; ++ct)
        sP[w][qo * 72 + ct * 16 + lr] = f2bf(sacc[ct][r]);
    }
    // O += P * V
#pragma unroll
    for (int kk = 0; kk < 2; ++kk) {
      short8 ap = *(const short8*)&sP[w][lr * 72 + kk * 32 + g * 8];
#pragma unroll
      for (int c4 = 0; c4 < 4; ++c4) {
        int row = c4 * 16 + lr;
        int sw = row & 7;
        short8 bv = *(const short8*)&sV[row * 64 + (((kk * 4 + g) ^ sw) * 8)];
        O[c4] = __builtin_amdgcn_mfma_f32_16x16x32_bf16(ap, bv, O[c4], 0, 0, 0);
      }
    }
    __syncthreads();
  }

  // epilogue: normalize, residual (+pooled q), store bf16
#pragma unroll
  for (int r = 0; r < 4; ++r) {
    int qg = q0 + g * 4 + r;
    if (qg >= NTOK) continue;
    float inv = 1.f / lrun[r];
#pragma unroll
    for (int c4 = 0; c4 < 4; ++c4) {
      float v = O[c4][r] * inv;
      int c = c4 * 16 + lr;
      if (qg >= 1) v += 8.f * bf2f(Qa[((size_t)bh * NPAD + qg) * AUG + c]);
      outA[((size_t)(b * NTOK + qg)) * DIM + h * HD + c] = f2bf(v);
    }
  }
}

// ---------------- launch ----------------
extern "C" void kernel_launch(void* const* d_in, const int* in_sizes, int n_in,
                              void* d_out, int out_size, void* d_ws, size_t ws_size,
                              hipStream_t stream) {
  (void)in_sizes; (void)n_in; (void)out_size; (void)ws_size;
  const float* x      = (const float*)d_in[0];
  const float* qkv_w  = (const float*)d_in[1];
  const float* qkv_b  = (const float*)d_in[2];
  const float* proj_w = (const float*)d_in[3];
  const float* proj_b = (const float*)d_in[4];
  const float* pw_q   = (const float*)d_in[5];
  const float* pw_k   = (const float*)d_in[6];
  const float* pw_v   = (const float*)d_in[7];
  const float* nw_q   = (const float*)d_in[8];
  const float* nb_q   = (const float*)d_in[9];
  const float* nw_k   = (const float*)d_in[10];
  const float* nb_k   = (const float*)d_in[11];
  const float* nw_v   = (const float*)d_in[12];
  const float* nb_v   = (const float*)d_in[13];
  const float* rel_t  = (const float*)d_in[14];
  const float* rel_h  = (const float*)d_in[15];
  const float* rel_w  = (const float*)d_in[16];
  float* out = (float*)d_out;

  char* ws = (char*)d_ws;
  size_t off = 0;
  auto alloc = [&](size_t bytes) -> void* {
    off = (off + 511) & ~(size_t)511;
    void* p = ws + off;
    off += bytes;
    return p;
  };
  u16*   xb     = (u16*)alloc((size_t)MP * DIM * 2);
  u16*   qkvwT  = (u16*)alloc((size_t)DIM3 * DIM * 2);
  u16*   projwT = (u16*)alloc((size_t)DIM * DIM * 2);
  float* qkvf   = (float*)alloc((size_t)3 * BHN * NPAD * HD * 4);
  u16*   Qa     = (u16*)alloc((size_t)BHN * NPAD * AUG * 2);
  u16*   Ka     = (u16*)alloc((size_t)BHN * NPAD * AUG * 2);
  u16*   Vt     = (u16*)alloc((size_t)BHN * HD * NPAD * 2);
  u16*   attnO  = (u16*)alloc((size_t)MP * DIM * 2);

  k_cast_x<<<dim3(MP * DIM / 1024), dim3(256), 0, stream>>>(x, xb);
  k_transpose_cast<<<dim3((DIM3 / 32) * (DIM / 32)), dim3(256), 0, stream>>>(qkv_w, qkvwT, DIM, DIM3);
  k_transpose_cast<<<dim3((DIM / 32) * (DIM / 32)), dim3(256), 0, stream>>>(proj_w, projwT, DIM, DIM);

  k_gemm<0><<<dim3(MP / 128, DIM3 / 128), dim3(256), 0, stream>>>(xb, qkvwT, qkv_b, qkvf);

  k_pool<<<dim3(3 * BHN * 29), dim3(256), 0, stream>>>(
      qkvf, pw_q, pw_k, pw_v, nw_q, nb_q, nw_k, nb_k, nw_v, nb_v,
      Qa, Ka, Vt);

  k_rel<<<dim3(BHN * 25), dim3(256), 0, stream>>>(rel_t, rel_h, rel_w, Qa);

  k_attn<<<dim3(BHN * 25), dim3(256), 0, stream>>>(Qa, Ka, Vt, attnO);

  k_gemm<1><<<dim3(MP / 128, DIM / 128), dim3(256), 0, stream>>>(attnO, projwT, proj_b, out);
}

// Round 4
// 307.768 us; speedup vs baseline: 2.1845x; 1.0396x over previous
//
#include <hip/hip_runtime.h>
#include <cstdint>
#include <cstddef>

typedef __attribute__((ext_vector_type(8))) short short8;
typedef __attribute__((ext_vector_type(4))) short short4v;
typedef __attribute__((ext_vector_type(4))) float f32x4;
typedef unsigned short u16;

#define DI __device__ __forceinline__

// ---------------- problem constants ----------------
constexpr int BATCH = 4;
constexpr int HEADS = 12, HD = 64;
constexpr int NTOK = 1569;          // T*H*W + 1
constexpr int NPAD = 1600;          // kv pad (25*64), qkvf row pad
constexpr int QPAD = 1664;          // q pad (13*128)
constexpr int DIM = 768, DIM3 = 2304;
constexpr int MROWS = BATCH * NTOK; // 6276
constexpr int MP = 6400;            // 50 * 128
constexpr int AUG = 128;            // 64 ch + 8 + 14 + 14 + pad
constexpr int BHN = BATCH * HEADS;  // 48
constexpr float LOG2E = 1.4426950408889634f;
constexpr float QSCALE = 0.125f * LOG2E;  // attn scale folded with log2e (exp2 domain)
constexpr float RESID = 8.0f / LOG2E;     // 1/QSCALE
constexpr float LN_EPS = 1e-5f;

// ---------------- helpers ----------------
DI u16 f2bf(float x) {
  union { float f; unsigned u; } v; v.f = x;
  unsigned r = v.u + 0x7FFFu + ((v.u >> 16) & 1u);
  return (u16)(r >> 16);
}
DI float bf2f(u16 h) {
  union { unsigned u; float f; } v; v.u = ((unsigned)h) << 16;
  return v.f;
}

typedef const __attribute__((address_space(1))) unsigned int gu32;
typedef __attribute__((address_space(3))) unsigned int lu32;
DI void gld16(const void* g, void* l) {
  __builtin_amdgcn_global_load_lds((gu32*)g, (lu32*)l, 16, 0, 0);
}

// max-reduce over each 16-lane row via DPP row_ror (VALU pipe, no LDS)
DI float rowmax16(float x) {
  int t;
  t = __builtin_amdgcn_update_dpp(__float_as_int(x), __float_as_int(x), 0x121, 0xF, 0xF, false);
  x = fmaxf(x, __int_as_float(t));
  t = __builtin_amdgcn_update_dpp(__float_as_int(x), __float_as_int(x), 0x122, 0xF, 0xF, false);
  x = fmaxf(x, __int_as_float(t));
  t = __builtin_amdgcn_update_dpp(__float_as_int(x), __float_as_int(x), 0x124, 0xF, 0xF, false);
  x = fmaxf(x, __int_as_float(t));
  t = __builtin_amdgcn_update_dpp(__float_as_int(x), __float_as_int(x), 0x128, 0xF, 0xF, false);
  x = fmaxf(x, __int_as_float(t));
  return x;
}

// ---------------- cast kernels ----------------
__global__ __launch_bounds__(256) void k_cast_x(const float* __restrict__ x,
                                                u16* __restrict__ xb) {
  int i = (blockIdx.x * 256 + threadIdx.x) * 4;
  if (i >= MP * DIM) return;
  int row = i / DIM;
  short4v o;
  if (row < MROWS) {
    float4 v = *(const float4*)(x + i);
    o.x = (short)f2bf(v.x); o.y = (short)f2bf(v.y);
    o.z = (short)f2bf(v.z); o.w = (short)f2bf(v.w);
  } else {
    o.x = 0; o.y = 0; o.z = 0; o.w = 0;
  }
  *(short4v*)(xb + i) = o;
}

// dst (NC, K) bf16 = transpose of src (K, NC) f32 — LDS 32x32 tile transpose
__global__ __launch_bounds__(256) void k_transpose_cast(const float* __restrict__ src,
                                                        u16* __restrict__ dst,
                                                        int K, int NC) {
  __shared__ float tile[32][33];
  const int ntiles = NC >> 5;
  const int bx = blockIdx.x % ntiles;  // n-tile
  const int by = blockIdx.x / ntiles;  // k-tile
  const int tx = threadIdx.x & 31, ty = threadIdx.x >> 5;
  const int n0 = bx * 32, k0 = by * 32;
#pragma unroll
  for (int r = 0; r < 32; r += 8)
    tile[ty + r][tx] = src[(size_t)(k0 + ty + r) * NC + n0 + tx];
  __syncthreads();
#pragma unroll
  for (int r = 0; r < 32; r += 8)
    dst[(size_t)(n0 + ty + r) * K + k0 + tx] = f2bf(tile[tx][ty + r]);
}

// ---------------- GEMM: C(M,N) = A(M,768)*Bt(N,768)^T + bias ----------------
template <int EPI>
__global__ __launch_bounds__(256) void k_gemm(const u16* __restrict__ A,
                                              const u16* __restrict__ Bt,
                                              const float* __restrict__ bias,
                                              float* __restrict__ out) {
  __shared__ __align__(16) u16 sA[128 * 64];
  __shared__ __align__(16) u16 sB[128 * 64];
  const int tid = threadIdx.x;
  const int w = tid >> 6, lane = tid & 63;
  const int g = lane >> 4, lr = lane & 15;
  const int brow = blockIdx.x * 128, bcol = blockIdx.y * 128;
  const int wr = w >> 1, wc = w & 1;

  f32x4 acc[4][4];
#pragma unroll
  for (int m = 0; m < 4; ++m)
#pragma unroll
    for (int n = 0; n < 4; ++n) {
      acc[m][n].x = 0.f; acc[m][n].y = 0.f; acc[m][n].z = 0.f; acc[m][n].w = 0.f;
    }

  for (int kt = 0; kt < 12; ++kt) {
    __syncthreads();
#pragma unroll
    for (int j = 0; j < 4; ++j) {
      int cb = (j * 4 + w) * 64;
      int chunk = cb + lane;
      int row = chunk >> 3, ch = chunk & 7;
      int gch = ch ^ (row & 7);
      gld16(A + (size_t)(brow + row) * DIM + kt * 64 + gch * 8, &sA[cb * 8]);
      gld16(Bt + (size_t)(bcol + row) * DIM + kt * 64 + gch * 8, &sB[cb * 8]);
    }
    __syncthreads();

    short8 af[4][2], bfr[4][2];
#pragma unroll
    for (int m = 0; m < 4; ++m) {
      int row = wr * 64 + m * 16 + lr;
      int sw = row & 7;
#pragma unroll
      for (int ks = 0; ks < 2; ++ks)
        af[m][ks] = *(const short8*)&sA[row * 64 + (((ks * 4 + g) ^ sw) * 8)];
    }
#pragma unroll
    for (int n = 0; n < 4; ++n) {
      int row = wc * 64 + n * 16 + lr;
      int sw = row & 7;
#pragma unroll
      for (int ks = 0; ks < 2; ++ks)
        bfr[n][ks] = *(const short8*)&sB[row * 64 + (((ks * 4 + g) ^ sw) * 8)];
    }
#pragma unroll
    for (int m = 0; m < 4; ++m)
#pragma unroll
      for (int n = 0; n < 4; ++n) {
        acc[m][n] = __builtin_amdgcn_mfma_f32_16x16x32_bf16(af[m][0], bfr[n][0], acc[m][n], 0, 0, 0);
        acc[m][n] = __builtin_amdgcn_mfma_f32_16x16x32_bf16(af[m][1], bfr[n][1], acc[m][n], 0, 0, 0);
      }
  }

#pragma unroll
  for (int m = 0; m < 4; ++m)
#pragma unroll
    for (int n = 0; n < 4; ++n) {
      int gj = bcol + wc * 64 + n * 16 + lr;
      float bv = bias[gj];
#pragma unroll
      for (int r = 0; r < 4; ++r) {
        int gm = brow + wr * 64 + m * 16 + g * 4 + r;
        if (gm >= MROWS) continue;
        float v = acc[m][n][r] + bv;
        if (EPI == 0) {
          int t = gj >= 1536 ? 2 : (gj >= 768 ? 1 : 0);
          int rem = gj - t * 768;
          int h = rem >> 6, c = rem & 63;
          int b = gm >= 3 * NTOK ? 3 : (gm >= 2 * NTOK ? 2 : (gm >= NTOK ? 1 : 0));
          int nt = gm - b * NTOK;
          out[(((size_t)(t * BATCH + b) * HEADS + h) * NPAD + nt) * HD + c] = v;
        } else {
          out[(size_t)gm * DIM + gj] = v;
        }
      }
    }
}

// ---------------- pool (depthwise conv3d) + LN + aug writes ----------------
DI float ldsrc(const float* __restrict__ src, int tt, int h2, int w2, int lane) {
  if ((unsigned)tt >= 8u || (unsigned)h2 >= 14u || (unsigned)w2 >= 14u) return 0.f;
  return src[(size_t)(1 + (tt * 14 + h2) * 14 + w2) * HD + lane];
}

__global__ __launch_bounds__(256, 4) void k_pool(
    const float* __restrict__ qkv,
    const float* __restrict__ pw_q, const float* __restrict__ pw_k, const float* __restrict__ pw_v,
    const float* __restrict__ nw_q, const float* __restrict__ nb_q,
    const float* __restrict__ nw_k, const float* __restrict__ nb_k,
    const float* __restrict__ nw_v, const float* __restrict__ nb_v,
    u16* __restrict__ Qa, u16* __restrict__ Ka, u16* __restrict__ Vt) {
  const int wv = threadIdx.x >> 6, lane = threadIdx.x & 63;
  const int unit = blockIdx.x % 29;
  const int taubh = blockIdx.x / 29;
  const int tau = taubh / BHN, bh = taubh % BHN;
  const float* src = qkv + ((size_t)tau * BHN + bh) * ((size_t)NPAD * HD);
  const float* nw = tau == 0 ? nw_q : tau == 1 ? nw_k : nw_v;
  const float* nb = tau == 0 ? nb_q : tau == 1 ? nb_k : nb_v;

  if (unit == 28) {
    if (wv == 0) {
      // CLS token (n = 0)
      float val = src[lane];
      float s = val, sq = val * val;
#pragma unroll
      for (int off = 1; off < 64; off <<= 1) { s += __shfl_xor(s, off); sq += __shfl_xor(sq, off); }
      float mean = s * (1.f / 64.f);
      float var = sq * (1.f / 64.f) - mean * mean;
      float ln = (val - mean) * rsqrtf(var + LN_EPS) * nw[lane] + nb[lane];
      if (tau == 0)      { size_t base = (size_t)bh * QPAD * AUG; Qa[base + lane] = f2bf(ln * QSCALE); Qa[base + 64 + lane] = 0; }
      else if (tau == 1) { size_t base = (size_t)bh * NPAD * AUG; Ka[base + lane] = f2bf(ln); Ka[base + 64 + lane] = 0; }
      else               { Vt[((size_t)bh * HD + lane) * NPAD] = f2bf(ln); }
    } else {
      // pad rows -> zero (Qa to QPAD, Ka/Vt to NPAD)
      int lim = (tau == 0) ? QPAD : NPAD;
      for (int n = 1569 + (wv - 1); n < lim; n += 3) {
        if (tau == 0) {
          size_t base = ((size_t)bh * QPAD + n) * AUG;
          Qa[base + lane] = 0; Qa[base + 64 + lane] = 0;
        } else if (tau == 1) {
          size_t base = ((size_t)bh * NPAD + n) * AUG;
          Ka[base + lane] = 0; Ka[base + 64 + lane] = 0;
        } else {
          Vt[((size_t)bh * HD + lane) * NPAD + n] = 0;
        }
      }
    }
    return;
  }

  const int th = unit * 4 + wv;          // 0..111
  const int t = th / 14, hh = th % 14;

  float wt[27];
  {
    const float* wp = (tau == 0 ? pw_q : tau == 1 ? pw_k : pw_v) + lane * 27;
#pragma unroll
    for (int j = 0; j < 27; ++j) wt[j] = wp[j];
  }

  float win[9][3];
#pragma unroll
  for (int dt = 0; dt < 3; ++dt)
#pragma unroll
    for (int dh = 0; dh < 3; ++dh) {
      win[dt * 3 + dh][0] = 0.f;
      win[dt * 3 + dh][1] = ldsrc(src, t + dt - 1, hh + dh - 1, 0, lane);
      win[dt * 3 + dh][2] = ldsrc(src, t + dt - 1, hh + dh - 1, 1, lane);
    }

#pragma unroll
  for (int ww = 0; ww < 14; ++ww) {
    float nxt[9];
#pragma unroll
    for (int dt = 0; dt < 3; ++dt)
#pragma unroll
      for (int dh = 0; dh < 3; ++dh)
        nxt[dt * 3 + dh] = ldsrc(src, t + dt - 1, hh + dh - 1, ww + 2, lane);

    float a = 0.f;
#pragma unroll
    for (int i = 0; i < 9; ++i)
      a += win[i][0] * wt[i * 3 + 0] + win[i][1] * wt[i * 3 + 1] + win[i][2] * wt[i * 3 + 2];

    float s = a, sq = a * a;
#pragma unroll
    for (int off = 1; off < 64; off <<= 1) { s += __shfl_xor(s, off); sq += __shfl_xor(sq, off); }
    float mean = s * (1.f / 64.f);
    float var = sq * (1.f / 64.f) - mean * mean;
    float ln = (a - mean) * rsqrtf(var + LN_EPS) * nw[lane] + nb[lane];

    const int n = 1 + (t * 14 + hh) * 14 + ww;
    if (tau == 0) {
      size_t base = ((size_t)bh * QPAD + n) * AUG;
      Qa[base + lane] = f2bf(ln * QSCALE);
      Qa[base + 64 + lane] = 0;  // k_rel fills lanes 64..99
    } else if (tau == 1) {
      size_t base = ((size_t)bh * NPAD + n) * AUG;
      Ka[base + lane] = f2bf(ln);
      u16 e = 0;
      if (lane == t || lane == 8 + hh || lane == 22 + ww) e = 0x3F80;  // bf16 1.0
      Ka[base + 64 + lane] = e;
    } else {
      Vt[((size_t)bh * HD + lane) * NPAD + n] = f2bf(ln);
    }

#pragma unroll
    for (int i = 0; i < 9; ++i) { win[i][0] = win[i][1]; win[i][1] = win[i][2]; win[i][2] = nxt[i]; }
  }
}

// ---------------- rel-pos dot table via MFMA ----------------
__global__ __launch_bounds__(256) void k_rel(const float* __restrict__ rel_t,
                                             const float* __restrict__ rel_h,
                                             const float* __restrict__ rel_w,
                                             u16* __restrict__ Qa) {
  __shared__ __align__(16) u16 sR[80 * 72];
  const int tid = threadIdx.x, w = tid >> 6, lane = tid & 63;
  const int g = lane >> 4, lr = lane & 15;
  const int bh = blockIdx.x / 25, qt = blockIdx.x % 25;

  for (int idx = tid; idx < 80 * 64; idx += 256) {
    int j = idx >> 6, c = idx & 63;
    float v = 0.f;
    if (j < 15)      v = rel_t[j * HD + c];
    else if (j < 42) v = rel_h[(j - 15) * HD + c];
    else if (j < 69) v = rel_w[(j - 42) * HD + c];
    sR[j * 72 + c] = f2bf(v * 8.f);
  }
  __syncthreads();

  const int q0 = qt * 64 + w * 16;
  short8 aq[2];
  {
    const u16* qrow = Qa + ((size_t)bh * QPAD + q0 + lr) * AUG;
    aq[0] = *(const short8*)(qrow + g * 8);
    aq[1] = *(const short8*)(qrow + 32 + g * 8);
  }

  f32x4 acc[5];
#pragma unroll
  for (int jt = 0; jt < 5; ++jt) {
    f32x4 a; a.x = 0.f; a.y = 0.f; a.z = 0.f; a.w = 0.f;
    int row = jt * 16 + lr;
    short8 b0 = *(const short8*)&sR[row * 72 + g * 8];
    short8 b1 = *(const short8*)&sR[row * 72 + (4 + g) * 8];
    a = __builtin_amdgcn_mfma_f32_16x16x32_bf16(aq[0], b0, a, 0, 0, 0);
    a = __builtin_amdgcn_mfma_f32_16x16x32_bf16(aq[1], b1, a, 0, 0, 0);
    acc[jt] = a;
  }

#pragma unroll
  for (int jt = 0; jt < 5; ++jt) {
    int j = jt * 16 + lr;
#pragma unroll
    for (int r = 0; r < 4; ++r) {
      int gq = q0 + g * 4 + r;
      if (gq < 1 || gq >= NTOK) continue;
      int p = gq - 1;
      int t = p / 196, pr = p - t * 196;
      int hh = pr / 14, ww = pr - hh * 14;
      int it = t + 7 - j;
      int ih = hh + 28 - j;
      int iw = ww + 55 - j;
      int i = -1;
      if ((unsigned)it < 8u) i = it;
      else if ((unsigned)ih < 14u) i = 8 + ih;
      else if ((unsigned)iw < 14u) i = 22 + iw;
      if (i >= 0)
        Qa[((size_t)bh * QPAD + gq) * AUG + 64 + i] = f2bf(acc[jt][r]);
    }
  }
}

// ---------------- fused flash attention (4 waves x 32 q-rows, 2-phase pipeline) ----------------
__global__ __launch_bounds__(256, 2) void k_attn(const u16* __restrict__ Qa,
                                                 const u16* __restrict__ Ka,
                                                 const u16* __restrict__ Vt,
                                                 u16* __restrict__ outA) {
  __shared__ __align__(16) u16 sK[2][64 * 128];  // K_aug tile, chunk-swizzled
  __shared__ __align__(16) u16 sV[2][80 * 64];   // V^T tile + ones row (64) + zero rows
  __shared__ __align__(16) u16 sP[4][32 * 72];   // per-wave P, padded stride 72
  const int tid = threadIdx.x, w = tid >> 6, lane = tid & 63;
  const int g = lane >> 4, lr = lane & 15;
  const int bh = blockIdx.x / 13, qt = blockIdx.x % 13;
  const int b = bh / HEADS, h = bh - b * HEADS;
  const int qw = qt * 128 + w * 32;   // wave's first q row

  // init sV tail rows 64..79 (row 64 = ones, 65..79 = zeros) in both buffers
  {
    unsigned* v0 = (unsigned*)&sV[0][64 * 64];
    unsigned* v1 = (unsigned*)&sV[1][64 * 64];
    for (int idx = tid; idx < 512; idx += 256) {
      unsigned val = (idx < 32) ? 0x3F803F80u : 0u;
      v0[idx] = val; v1[idx] = val;
    }
  }

  // load Q fragments (held in registers for the whole loop)
  short8 aq[2][4];
#pragma unroll
  for (int f = 0; f < 2; ++f) {
    const u16* qrow = Qa + ((size_t)bh * QPAD + qw + f * 16 + lr) * AUG;
#pragma unroll
    for (int ks = 0; ks < 4; ++ks) aq[f][ks] = *(const short8*)(qrow + ks * 32 + g * 8);
  }

  auto stage = [&](int buf, int kb) {
    const u16* Kb = Ka + ((size_t)bh * NPAD + kb * 64) * AUG;
#pragma unroll
    for (int j = 0; j < 4; ++j) {
      int chunk = j * 256 + tid;
      int row = chunk >> 4, ch = chunk & 15;
      int gch = ch ^ (row & 7);
      gld16(Kb + (size_t)row * AUG + gch * 8, &sK[buf][(j * 256 + w * 64) * 8]);
    }
    const u16* Vb = Vt + (size_t)bh * HD * NPAD + kb * 64;
#pragma unroll
    for (int j = 0; j < 2; ++j) {
      int chunk = j * 256 + tid;
      int row = chunk >> 3, ch = chunk & 7;
      int gch = ch ^ (row & 7);
      gld16(Vb + (size_t)row * NPAD + gch * 8, &sV[buf][(j * 256 + w * 64) * 8]);
    }
  };

  f32x4 O[2][5];
#pragma unroll
  for (int f = 0; f < 2; ++f)
#pragma unroll
    for (int c4 = 0; c4 < 5; ++c4) { O[f][c4].x = 0.f; O[f][c4].y = 0.f; O[f][c4].z = 0.f; O[f][c4].w = 0.f; }
  float mrun[2][4];
#pragma unroll
  for (int f = 0; f < 2; ++f)
#pragma unroll
    for (int r = 0; r < 4; ++r) mrun[f][r] = -1e30f;

  stage(0, 0);
  __syncthreads();

  int cur = 0;
  for (int kb = 0; kb < 25; ++kb) {
    if (kb < 24) stage(cur ^ 1, kb + 1);

    // S = Q_aug * K_aug^T  (D: row q = g*4+r, col key = lr)
    f32x4 sacc[2][4];
    __builtin_amdgcn_s_setprio(1);
#pragma unroll
    for (int ct = 0; ct < 4; ++ct) {
      int row = ct * 16 + lr;
      int sw = row & 7;
      short8 bk[4];
#pragma unroll
      for (int ks = 0; ks < 4; ++ks)
        bk[ks] = *(const short8*)&sK[cur][row * 128 + (((ks * 4 + g) ^ sw) * 8)];
#pragma unroll
      for (int f = 0; f < 2; ++f) {
        f32x4 a; a.x = 0.f; a.y = 0.f; a.z = 0.f; a.w = 0.f;
#pragma unroll
        for (int ks = 0; ks < 4; ++ks)
          a = __builtin_amdgcn_mfma_f32_16x16x32_bf16(aq[f][ks], bk[ks], a, 0, 0, 0);
        sacc[f][ct] = a;
      }
    }
    __builtin_amdgcn_s_setprio(0);

    if (kb == 24) {  // tail mask: valid keys < NTOK (ct=2: lr==0 only; ct=3: none)
#pragma unroll
      for (int f = 0; f < 2; ++f)
#pragma unroll
        for (int r = 0; r < 4; ++r) {
          sacc[f][2][r] = (lr < 1) ? sacc[f][2][r] : -1e30f;
          sacc[f][3][r] = -1e30f;
        }
    }

    // online softmax (exp2 domain); row-sum comes free from V ones-row
#pragma unroll
    for (int f = 0; f < 2; ++f)
#pragma unroll
      for (int r = 0; r < 4; ++r) {
        float mx = fmaxf(fmaxf(sacc[f][0][r], sacc[f][1][r]), fmaxf(sacc[f][2][r], sacc[f][3][r]));
        mx = rowmax16(mx);
        float om = mrun[f][r];
        float nm = fmaxf(om, mx);
        float sc = exp2f(om - nm);
        mrun[f][r] = nm;
#pragma unroll
        for (int c4 = 0; c4 < 5; ++c4) O[f][c4][r] *= sc;
        int qo = f * 16 + g * 4 + r;
#pragma unroll
        for (int ct = 0; ct < 4; ++ct) {
          float p = exp2f(sacc[f][ct][r] - nm);
          sP[w][qo * 72 + ct * 16 + lr] = (u16)(__float_as_uint(p) >> 16);  // trunc bf16
        }
      }

    // O += P * V^T   (5th c4 block = ones row -> row sums in O[f][4], channel 64 = lr 0)
    __builtin_amdgcn_s_setprio(1);
#pragma unroll
    for (int kk = 0; kk < 2; ++kk) {
      short8 ap[2];
#pragma unroll
      for (int f = 0; f < 2; ++f)
        ap[f] = *(const short8*)&sP[w][(f * 16 + lr) * 72 + kk * 32 + g * 8];
#pragma unroll
      for (int c4 = 0; c4 < 5; ++c4) {
        int row = c4 * 16 + lr;
        int sw = row & 7;
        short8 bv = *(const short8*)&sV[cur][row * 64 + (((kk * 4 + g) ^ sw) * 8)];
#pragma unroll
        for (int f = 0; f < 2; ++f)
          O[f][c4] = __builtin_amdgcn_mfma_f32_16x16x32_bf16(ap[f], bv, O[f][c4], 0, 0, 0);
      }
    }
    __builtin_amdgcn_s_setprio(0);

    __syncthreads();
    cur ^= 1;
  }

  // epilogue: l from ones-channel (col lr==0 of c4=4), normalize, residual, store
#pragma unroll
  for (int f = 0; f < 2; ++f)
#pragma unroll
    for (int r = 0; r < 4; ++r) {
      float l = __shfl(O[f][4][r], lane & 48);  // broadcast lr=0 within 16-lane group
      float inv = 1.f / l;
      int qg = qw + f * 16 + g * 4 + r;
      if (qg >= NTOK) continue;
#pragma unroll
      for (int c4 = 0; c4 < 4; ++c4) {
        float v = O[f][c4][r] * inv;
        int c = c4 * 16 + lr;
        if (qg >= 1) v += RESID * bf2f(Qa[((size_t)bh * QPAD + qg) * AUG + c]);
        outA[((size_t)(b * NTOK + qg)) * DIM + h * HD + c] = f2bf(v);
      }
    }
}

// ---------------- launch ----------------
extern "C" void kernel_launch(void* const* d_in, const int* in_sizes, int n_in,
                              void* d_out, int out_size, void* d_ws, size_t ws_size,
                              hipStream_t stream) {
  (void)in_sizes; (void)n_in; (void)out_size; (void)ws_size;
  const float* x      = (const float*)d_in[0];
  const float* qkv_w  = (const float*)d_in[1];
  const float* qkv_b  = (const float*)d_in[2];
  const float* proj_w = (const float*)d_in[3];
  const float* proj_b = (const float*)d_in[4];
  const float* pw_q   = (const float*)d_in[5];
  const float* pw_k   = (const float*)d_in[6];
  const float* pw_v   = (const float*)d_in[7];
  const float* nw_q   = (const float*)d_in[8];
  const float* nb_q   = (const float*)d_in[9];
  const float* nw_k   = (const float*)d_in[10];
  const float* nb_k   = (const float*)d_in[11];
  const float* nw_v   = (const float*)d_in[12];
  const float* nb_v   = (const float*)d_in[13];
  const float* rel_t  = (const float*)d_in[14];
  const float* rel_h  = (const float*)d_in[15];
  const float* rel_w  = (const float*)d_in[16];
  float* out = (float*)d_out;

  char* ws = (char*)d_ws;
  size_t off = 0;
  auto alloc = [&](size_t bytes) -> void* {
    off = (off + 511) & ~(size_t)511;
    void* p = ws + off;
    off += bytes;
    return p;
  };
  u16*   xb     = (u16*)alloc((size_t)MP * DIM * 2);
  u16*   qkvwT  = (u16*)alloc((size_t)DIM3 * DIM * 2);
  u16*   projwT = (u16*)alloc((size_t)DIM * DIM * 2);
  float* qkvf   = (float*)alloc((size_t)3 * BHN * NPAD * HD * 4);
  u16*   Qa     = (u16*)alloc((size_t)BHN * QPAD * AUG * 2);
  u16*   Ka     = (u16*)alloc((size_t)BHN * NPAD * AUG * 2);
  u16*   Vt     = (u16*)alloc((size_t)BHN * HD * NPAD * 2);
  u16*   attnO  = (u16*)alloc((size_t)MP * DIM * 2);

  k_cast_x<<<dim3(MP * DIM / 1024), dim3(256), 0, stream>>>(x, xb);
  k_transpose_cast<<<dim3((DIM3 / 32) * (DIM / 32)), dim3(256), 0, stream>>>(qkv_w, qkvwT, DIM, DIM3);
  k_transpose_cast<<<dim3((DIM / 32) * (DIM / 32)), dim3(256), 0, stream>>>(proj_w, projwT, DIM, DIM);

  k_gemm<0><<<dim3(MP / 128, DIM3 / 128), dim3(256), 0, stream>>>(xb, qkvwT, qkv_b, qkvf);

  k_pool<<<dim3(3 * BHN * 29), dim3(256), 0, stream>>>(
      qkvf, pw_q, pw_k, pw_v, nw_q, nb_q, nw_k, nb_k, nw_v, nb_v,
      Qa, Ka, Vt);

  k_rel<<<dim3(BHN * 25), dim3(256), 0, stream>>>(rel_t, rel_h, rel_w, Qa);

  k_attn<<<dim3(BHN * 13), dim3(256), 0, stream>>>(Qa, Ka, Vt, attnO);

  k_gemm<1><<<dim3(MP / 128, DIM / 128), dim3(256), 0, stream>>>(attnO, projwT, proj_b, out);
}

// Round 5
// 279.910 us; speedup vs baseline: 2.4019x; 1.0995x over previous
//
#include <hip/hip_runtime.h>
#include <cstdint>
#include <cstddef>

typedef __attribute__((ext_vector_type(8))) short short8;
typedef __attribute__((ext_vector_type(4))) short short4v;
typedef __attribute__((ext_vector_type(4))) float f32x4;
typedef unsigned short u16;

#define DI __device__ __forceinline__

// ---------------- problem constants ----------------
constexpr int BATCH = 4;
constexpr int HEADS = 12, HD = 64;
constexpr int NTOK = 1569;          // T*H*W + 1
constexpr int NPAD = 1600;          // kv pad (25*64), qkvf row pad
constexpr int QPAD = 1664;          // q pad (13*128)
constexpr int DIM = 768, DIM3 = 2304;
constexpr int MROWS = BATCH * NTOK; // 6276
constexpr int MP = 6400;            // 50 * 128
constexpr int AUG = 128;            // 64 ch + 8 + 14 + 14 + pad
constexpr int BHN = BATCH * HEADS;  // 48
constexpr float LOG2E = 1.4426950408889634f;
constexpr float QSCALE = 0.125f * LOG2E;  // attn scale folded with log2e (exp2 domain)
constexpr float RESID = 8.0f / LOG2E;     // 1/QSCALE
constexpr float LN_EPS = 1e-5f;

// ---------------- helpers ----------------
DI u16 f2bf(float x) {
  union { float f; unsigned u; } v; v.f = x;
  unsigned r = v.u + 0x7FFFu + ((v.u >> 16) & 1u);
  return (u16)(r >> 16);
}
DI float bf2f(u16 h) {
  union { unsigned u; float f; } v; v.u = ((unsigned)h) << 16;
  return v.f;
}

typedef const __attribute__((address_space(1))) unsigned int gu32;
typedef __attribute__((address_space(3))) unsigned int lu32;
DI void gld16(const void* g, void* l) {
  __builtin_amdgcn_global_load_lds((gu32*)g, (lu32*)l, 16, 0, 0);
}

// max / sum reduce over each 16-lane row via DPP row_ror (VALU pipe, no LDS)
DI float rowmax16(float x) {
  int t;
  t = __builtin_amdgcn_update_dpp(__float_as_int(x), __float_as_int(x), 0x121, 0xF, 0xF, false);
  x = fmaxf(x, __int_as_float(t));
  t = __builtin_amdgcn_update_dpp(__float_as_int(x), __float_as_int(x), 0x122, 0xF, 0xF, false);
  x = fmaxf(x, __int_as_float(t));
  t = __builtin_amdgcn_update_dpp(__float_as_int(x), __float_as_int(x), 0x124, 0xF, 0xF, false);
  x = fmaxf(x, __int_as_float(t));
  t = __builtin_amdgcn_update_dpp(__float_as_int(x), __float_as_int(x), 0x128, 0xF, 0xF, false);
  x = fmaxf(x, __int_as_float(t));
  return x;
}
DI float rowsum16(float x) {
  int t;
  t = __builtin_amdgcn_update_dpp(__float_as_int(x), __float_as_int(x), 0x121, 0xF, 0xF, false);
  x += __int_as_float(t);
  t = __builtin_amdgcn_update_dpp(__float_as_int(x), __float_as_int(x), 0x122, 0xF, 0xF, false);
  x += __int_as_float(t);
  t = __builtin_amdgcn_update_dpp(__float_as_int(x), __float_as_int(x), 0x124, 0xF, 0xF, false);
  x += __int_as_float(t);
  t = __builtin_amdgcn_update_dpp(__float_as_int(x), __float_as_int(x), 0x128, 0xF, 0xF, false);
  x += __int_as_float(t);
  return x;
}

// ---------------- cast kernels ----------------
__global__ __launch_bounds__(256) void k_cast_x(const float* __restrict__ x,
                                                u16* __restrict__ xb) {
  int i = (blockIdx.x * 256 + threadIdx.x) * 4;
  if (i >= MP * DIM) return;
  int row = i / DIM;
  short4v o;
  if (row < MROWS) {
    float4 v = *(const float4*)(x + i);
    o.x = (short)f2bf(v.x); o.y = (short)f2bf(v.y);
    o.z = (short)f2bf(v.z); o.w = (short)f2bf(v.w);
  } else {
    o.x = 0; o.y = 0; o.z = 0; o.w = 0;
  }
  *(short4v*)(xb + i) = o;
}

// dst (NC, K) bf16 = transpose of src (K, NC) f32 — LDS 32x32 tile transpose
__global__ __launch_bounds__(256) void k_transpose_cast(const float* __restrict__ src,
                                                        u16* __restrict__ dst,
                                                        int K, int NC) {
  __shared__ float tile[32][33];
  const int ntiles = NC >> 5;
  const int bx = blockIdx.x % ntiles;  // n-tile
  const int by = blockIdx.x / ntiles;  // k-tile
  const int tx = threadIdx.x & 31, ty = threadIdx.x >> 5;
  const int n0 = bx * 32, k0 = by * 32;
#pragma unroll
  for (int r = 0; r < 32; r += 8)
    tile[ty + r][tx] = src[(size_t)(k0 + ty + r) * NC + n0 + tx];
  __syncthreads();
#pragma unroll
  for (int r = 0; r < 32; r += 8)
    dst[(size_t)(n0 + ty + r) * K + k0 + tx] = f2bf(tile[tx][ty + r]);
}

// ---------------- GEMM: C(M,N) = A(M,768)*Bt(N,768)^T + bias ----------------
template <int EPI>
__global__ __launch_bounds__(256) void k_gemm(const u16* __restrict__ A,
                                              const u16* __restrict__ Bt,
                                              const float* __restrict__ bias,
                                              float* __restrict__ out) {
  __shared__ __align__(16) u16 sA[128 * 64];
  __shared__ __align__(16) u16 sB[128 * 64];
  const int tid = threadIdx.x;
  const int w = tid >> 6, lane = tid & 63;
  const int g = lane >> 4, lr = lane & 15;
  const int brow = blockIdx.x * 128, bcol = blockIdx.y * 128;
  const int wr = w >> 1, wc = w & 1;

  f32x4 acc[4][4];
#pragma unroll
  for (int m = 0; m < 4; ++m)
#pragma unroll
    for (int n = 0; n < 4; ++n) {
      acc[m][n].x = 0.f; acc[m][n].y = 0.f; acc[m][n].z = 0.f; acc[m][n].w = 0.f;
    }

  for (int kt = 0; kt < 12; ++kt) {
    __syncthreads();
#pragma unroll
    for (int j = 0; j < 4; ++j) {
      int cb = (j * 4 + w) * 64;
      int chunk = cb + lane;
      int row = chunk >> 3, ch = chunk & 7;
      int gch = ch ^ (row & 7);
      gld16(A + (size_t)(brow + row) * DIM + kt * 64 + gch * 8, &sA[cb * 8]);
      gld16(Bt + (size_t)(bcol + row) * DIM + kt * 64 + gch * 8, &sB[cb * 8]);
    }
    __syncthreads();

    short8 af[4][2], bfr[4][2];
#pragma unroll
    for (int m = 0; m < 4; ++m) {
      int row = wr * 64 + m * 16 + lr;
      int sw = row & 7;
#pragma unroll
      for (int ks = 0; ks < 2; ++ks)
        af[m][ks] = *(const short8*)&sA[row * 64 + (((ks * 4 + g) ^ sw) * 8)];
    }
#pragma unroll
    for (int n = 0; n < 4; ++n) {
      int row = wc * 64 + n * 16 + lr;
      int sw = row & 7;
#pragma unroll
      for (int ks = 0; ks < 2; ++ks)
        bfr[n][ks] = *(const short8*)&sB[row * 64 + (((ks * 4 + g) ^ sw) * 8)];
    }
#pragma unroll
    for (int m = 0; m < 4; ++m)
#pragma unroll
      for (int n = 0; n < 4; ++n) {
        acc[m][n] = __builtin_amdgcn_mfma_f32_16x16x32_bf16(af[m][0], bfr[n][0], acc[m][n], 0, 0, 0);
        acc[m][n] = __builtin_amdgcn_mfma_f32_16x16x32_bf16(af[m][1], bfr[n][1], acc[m][n], 0, 0, 0);
      }
  }

#pragma unroll
  for (int m = 0; m < 4; ++m)
#pragma unroll
    for (int n = 0; n < 4; ++n) {
      int gj = bcol + wc * 64 + n * 16 + lr;
      float bv = bias[gj];
#pragma unroll
      for (int r = 0; r < 4; ++r) {
        int gm = brow + wr * 64 + m * 16 + g * 4 + r;
        if (gm >= MROWS) continue;
        float v = acc[m][n][r] + bv;
        if (EPI == 0) {
          int t = gj >= 1536 ? 2 : (gj >= 768 ? 1 : 0);
          int rem = gj - t * 768;
          int h = rem >> 6, c = rem & 63;
          int b = gm >= 3 * NTOK ? 3 : (gm >= 2 * NTOK ? 2 : (gm >= NTOK ? 1 : 0));
          int nt = gm - b * NTOK;
          out[(((size_t)(t * BATCH + b) * HEADS + h) * NPAD + nt) * HD + c] = v;
        } else {
          out[(size_t)gm * DIM + gj] = v;
        }
      }
    }
}

// ---------------- pool (depthwise conv3d) + LN + aug writes ----------------
DI float ldsrc(const float* __restrict__ src, int tt, int h2, int w2, int lane) {
  if ((unsigned)tt >= 8u || (unsigned)h2 >= 14u || (unsigned)w2 >= 14u) return 0.f;
  return src[(size_t)(1 + (tt * 14 + h2) * 14 + w2) * HD + lane];
}

__global__ __launch_bounds__(256, 4) void k_pool(
    const float* __restrict__ qkv,
    const float* __restrict__ pw_q, const float* __restrict__ pw_k, const float* __restrict__ pw_v,
    const float* __restrict__ nw_q, const float* __restrict__ nb_q,
    const float* __restrict__ nw_k, const float* __restrict__ nb_k,
    const float* __restrict__ nw_v, const float* __restrict__ nb_v,
    u16* __restrict__ Qa, u16* __restrict__ Ka, u16* __restrict__ Vt) {
  const int wv = threadIdx.x >> 6, lane = threadIdx.x & 63;
  const int unit = blockIdx.x % 29;
  const int taubh = blockIdx.x / 29;
  const int tau = taubh / BHN, bh = taubh % BHN;
  const float* src = qkv + ((size_t)tau * BHN + bh) * ((size_t)NPAD * HD);
  const float* nw = tau == 0 ? nw_q : tau == 1 ? nw_k : nw_v;
  const float* nb = tau == 0 ? nb_q : tau == 1 ? nb_k : nb_v;

  if (unit == 28) {
    if (wv == 0) {
      // CLS token (n = 0)
      float val = src[lane];
      float s = val, sq = val * val;
#pragma unroll
      for (int off = 1; off < 64; off <<= 1) { s += __shfl_xor(s, off); sq += __shfl_xor(sq, off); }
      float mean = s * (1.f / 64.f);
      float var = sq * (1.f / 64.f) - mean * mean;
      float ln = (val - mean) * rsqrtf(var + LN_EPS) * nw[lane] + nb[lane];
      if (tau == 0)      { size_t base = (size_t)bh * QPAD * AUG; Qa[base + lane] = f2bf(ln * QSCALE); Qa[base + 64 + lane] = 0; }
      else if (tau == 1) { size_t base = (size_t)bh * NPAD * AUG; Ka[base + lane] = f2bf(ln); Ka[base + 64 + lane] = 0; }
      else               { Vt[((size_t)bh * HD + lane) * NPAD] = f2bf(ln); }
    } else {
      // pad rows -> zero (Qa to QPAD, Ka/Vt to NPAD)
      int lim = (tau == 0) ? QPAD : NPAD;
      for (int n = 1569 + (wv - 1); n < lim; n += 3) {
        if (tau == 0) {
          size_t base = ((size_t)bh * QPAD + n) * AUG;
          Qa[base + lane] = 0; Qa[base + 64 + lane] = 0;
        } else if (tau == 1) {
          size_t base = ((size_t)bh * NPAD + n) * AUG;
          Ka[base + lane] = 0; Ka[base + 64 + lane] = 0;
        } else {
          Vt[((size_t)bh * HD + lane) * NPAD + n] = 0;
        }
      }
    }
    return;
  }

  const int th = unit * 4 + wv;          // 0..111
  const int t = th / 14, hh = th % 14;

  float wt[27];
  {
    const float* wp = (tau == 0 ? pw_q : tau == 1 ? pw_k : pw_v) + lane * 27;
#pragma unroll
    for (int j = 0; j < 27; ++j) wt[j] = wp[j];
  }

  float win[9][3];
#pragma unroll
  for (int dt = 0; dt < 3; ++dt)
#pragma unroll
    for (int dh = 0; dh < 3; ++dh) {
      win[dt * 3 + dh][0] = 0.f;
      win[dt * 3 + dh][1] = ldsrc(src, t + dt - 1, hh + dh - 1, 0, lane);
      win[dt * 3 + dh][2] = ldsrc(src, t + dt - 1, hh + dh - 1, 1, lane);
    }

#pragma unroll
  for (int ww = 0; ww < 14; ++ww) {
    float nxt[9];
#pragma unroll
    for (int dt = 0; dt < 3; ++dt)
#pragma unroll
      for (int dh = 0; dh < 3; ++dh)
        nxt[dt * 3 + dh] = ldsrc(src, t + dt - 1, hh + dh - 1, ww + 2, lane);

    float a = 0.f;
#pragma unroll
    for (int i = 0; i < 9; ++i)
      a += win[i][0] * wt[i * 3 + 0] + win[i][1] * wt[i * 3 + 1] + win[i][2] * wt[i * 3 + 2];

    float s = a, sq = a * a;
#pragma unroll
    for (int off = 1; off < 64; off <<= 1) { s += __shfl_xor(s, off); sq += __shfl_xor(sq, off); }
    float mean = s * (1.f / 64.f);
    float var = sq * (1.f / 64.f) - mean * mean;
    float ln = (a - mean) * rsqrtf(var + LN_EPS) * nw[lane] + nb[lane];

    const int n = 1 + (t * 14 + hh) * 14 + ww;
    if (tau == 0) {
      size_t base = ((size_t)bh * QPAD + n) * AUG;
      Qa[base + lane] = f2bf(ln * QSCALE);
      Qa[base + 64 + lane] = 0;  // k_rel fills lanes 64..99
    } else if (tau == 1) {
      size_t base = ((size_t)bh * NPAD + n) * AUG;
      Ka[base + lane] = f2bf(ln);
      u16 e = 0;
      if (lane == t || lane == 8 + hh || lane == 22 + ww) e = 0x3F80;  // bf16 1.0
      Ka[base + 64 + lane] = e;
    } else {
      Vt[((size_t)bh * HD + lane) * NPAD + n] = f2bf(ln);
    }

#pragma unroll
    for (int i = 0; i < 9; ++i) { win[i][0] = win[i][1]; win[i][1] = win[i][2]; win[i][2] = nxt[i]; }
  }
}

// ---------------- rel-pos dot table via MFMA ----------------
__global__ __launch_bounds__(256) void k_rel(const float* __restrict__ rel_t,
                                             const float* __restrict__ rel_h,
                                             const float* __restrict__ rel_w,
                                             u16* __restrict__ Qa) {
  __shared__ __align__(16) u16 sR[80 * 72];
  const int tid = threadIdx.x, w = tid >> 6, lane = tid & 63;
  const int g = lane >> 4, lr = lane & 15;
  const int bh = blockIdx.x / 25, qt = blockIdx.x % 25;

  for (int idx = tid; idx < 80 * 64; idx += 256) {
    int j = idx >> 6, c = idx & 63;
    float v = 0.f;
    if (j < 15)      v = rel_t[j * HD + c];
    else if (j < 42) v = rel_h[(j - 15) * HD + c];
    else if (j < 69) v = rel_w[(j - 42) * HD + c];
    sR[j * 72 + c] = f2bf(v * 8.f);
  }
  __syncthreads();

  const int q0 = qt * 64 + w * 16;
  short8 aq[2];
  {
    const u16* qrow = Qa + ((size_t)bh * QPAD + q0 + lr) * AUG;
    aq[0] = *(const short8*)(qrow + g * 8);
    aq[1] = *(const short8*)(qrow + 32 + g * 8);
  }

  f32x4 acc[5];
#pragma unroll
  for (int jt = 0; jt < 5; ++jt) {
    f32x4 a; a.x = 0.f; a.y = 0.f; a.z = 0.f; a.w = 0.f;
    int row = jt * 16 + lr;
    short8 b0 = *(const short8*)&sR[row * 72 + g * 8];
    short8 b1 = *(const short8*)&sR[row * 72 + (4 + g) * 8];
    a = __builtin_amdgcn_mfma_f32_16x16x32_bf16(aq[0], b0, a, 0, 0, 0);
    a = __builtin_amdgcn_mfma_f32_16x16x32_bf16(aq[1], b1, a, 0, 0, 0);
    acc[jt] = a;
  }

#pragma unroll
  for (int jt = 0; jt < 5; ++jt) {
    int j = jt * 16 + lr;
#pragma unroll
    for (int r = 0; r < 4; ++r) {
      int gq = q0 + g * 4 + r;
      if (gq < 1 || gq >= NTOK) continue;
      int p = gq - 1;
      int t = p / 196, pr = p - t * 196;
      int hh = pr / 14, ww = pr - hh * 14;
      int it = t + 7 - j;
      int ih = hh + 28 - j;
      int iw = ww + 55 - j;
      int i = -1;
      if ((unsigned)it < 8u) i = it;
      else if ((unsigned)ih < 14u) i = 8 + ih;
      else if ((unsigned)iw < 14u) i = 22 + iw;
      if (i >= 0)
        Qa[((size_t)bh * QPAD + gq) * AUG + 64 + i] = f2bf(acc[jt][r]);
    }
  }
}

// ---------------- fused flash attention (KV-split x2, 3 blocks/CU) ----------------
// Block = (bh, half, qtile): 128 q rows, half of the kv tiles. Writes normalized
// bf16 partial O + (m, l) f32; k_comb merges the two halves.
__global__ __launch_bounds__(256, 3) void k_attn(const u16* __restrict__ Qa,
                                                 const u16* __restrict__ Ka,
                                                 const u16* __restrict__ Vt,
                                                 u16* __restrict__ Opart,
                                                 float* __restrict__ ml) {
  __shared__ __align__(16) u16 sK[64 * 128];     // K_aug tile, single-buffered
  __shared__ __align__(16) u16 sV[2][64 * 64];   // V^T tile, double-buffered
  __shared__ __align__(16) u16 sP[4][32 * 72];   // per-wave P, col-XOR swizzled
  const int tid = threadIdx.x, w = tid >> 6, lane = tid & 63;
  const int g = lane >> 4, lr = lane & 15;
  // XCD-chunked swizzle: 1248 blocks = 8 XCDs x 156 (= 3 bh per XCD -> L2-resident K/V)
  const int bid = blockIdx.x;
  const int swz = (bid & 7) * 156 + (bid >> 3);
  const int bh = swz / 26, rem2 = swz % 26;
  const int half = rem2 / 13, qt = rem2 % 13;
  const int qw = qt * 128 + w * 32;
  const int kb0 = half * 13;            // half0: tiles 0..12, half1: 13..24
  const int kbN = half ? 12 : 13;

  // Q fragments (registers, whole loop)
  short8 aq[2][4];
#pragma unroll
  for (int f = 0; f < 2; ++f) {
    const u16* qrow = Qa + ((size_t)bh * QPAD + qw + f * 16 + lr) * AUG;
#pragma unroll
    for (int ks = 0; ks < 4; ++ks) aq[f][ks] = *(const short8*)(qrow + ks * 32 + g * 8);
  }

  // hoisted staging pointers (advance by constant per tile)
  const u16* kgp[4];
  u16* kld[4];
#pragma unroll
  for (int j = 0; j < 4; ++j) {
    int idx = j * 256 + tid;
    int row = idx >> 4, ch = idx & 15;
    int gch = ch ^ (row & 7);
    kgp[j] = Ka + ((size_t)bh * NPAD + kb0 * 64 + row) * AUG + gch * 8;
    kld[j] = &sK[(j * 256 + w * 64) * 8];
  }
  const u16* vgp[2];
  int vld[2];
#pragma unroll
  for (int j = 0; j < 2; ++j) {
    int idx = j * 256 + tid;
    int row = idx >> 3, ch = idx & 7;
    int gch = ch ^ (row & 7);
    vgp[j] = Vt + ((size_t)bh * HD + row) * NPAD + kb0 * 64 + gch * 8;
    vld[j] = (j * 256 + w * 64) * 8;
  }

  // prologue stage (tile kb0 -> sK, sV[0])
#pragma unroll
  for (int j = 0; j < 4; ++j) { gld16(kgp[j], kld[j]); kgp[j] += 64 * AUG; }
#pragma unroll
  for (int j = 0; j < 2; ++j) { gld16(vgp[j], &sV[0][vld[j]]); vgp[j] += 64; }
  __syncthreads();

  f32x4 O[2][4];
#pragma unroll
  for (int f = 0; f < 2; ++f)
#pragma unroll
    for (int c4 = 0; c4 < 4; ++c4) { O[f][c4].x = 0.f; O[f][c4].y = 0.f; O[f][c4].z = 0.f; O[f][c4].w = 0.f; }
  float mrun[2][4], lrun[2][4];
#pragma unroll
  for (int f = 0; f < 2; ++f)
#pragma unroll
    for (int r = 0; r < 4; ++r) { mrun[f][r] = -1e30f; lrun[f][r] = 0.f; }

  int cc[4];
#pragma unroll
  for (int ct = 0; ct < 4; ++ct) cc[ct] = ((ct ^ g) & 3) << 4;  // sP col swizzle
  const int bx = (lr >> 2) & 3;                                 // sP read swizzle

  int cur = 0;
  for (int it = 0; it < kbN; ++it) {
    // ---- QK from sK ----
    f32x4 sacc[2][4];
    __builtin_amdgcn_s_setprio(1);
#pragma unroll
    for (int ct = 0; ct < 4; ++ct) {
      int row = ct * 16 + lr;
      int sw = row & 7;
      short8 bk[4];
#pragma unroll
      for (int ks = 0; ks < 4; ++ks)
        bk[ks] = *(const short8*)&sK[row * 128 + (((ks * 4 + g) ^ sw) << 3)];
#pragma unroll
      for (int f = 0; f < 2; ++f) {
        f32x4 a; a.x = 0.f; a.y = 0.f; a.z = 0.f; a.w = 0.f;
#pragma unroll
        for (int ks = 0; ks < 4; ++ks)
          a = __builtin_amdgcn_mfma_f32_16x16x32_bf16(aq[f][ks], bk[ks], a, 0, 0, 0);
        sacc[f][ct] = a;
      }
    }
    __builtin_amdgcn_s_setprio(0);
    __syncthreads();  // barrier A: all QK reads of sK done

    // stage next tile (K -> sK, V -> sV[cur^1]); consumed after barrier B
    if (it + 1 < kbN) {
#pragma unroll
      for (int j = 0; j < 4; ++j) { gld16(kgp[j], kld[j]); kgp[j] += 64 * AUG; }
#pragma unroll
      for (int j = 0; j < 2; ++j) { gld16(vgp[j], &sV[cur ^ 1][vld[j]]); vgp[j] += 64; }
    }

    if (kb0 + it == 24) {  // tail mask (keys >= NTOK)
#pragma unroll
      for (int f = 0; f < 2; ++f)
#pragma unroll
        for (int r = 0; r < 4; ++r) {
          sacc[f][2][r] = (lr < 1) ? sacc[f][2][r] : -1e30f;
          sacc[f][3][r] = -1e30f;
        }
    }

    // ---- online softmax (exp2 domain, defer-max) ----
#pragma unroll
    for (int f = 0; f < 2; ++f)
#pragma unroll
      for (int r = 0; r < 4; ++r) {
        float mx = fmaxf(fmaxf(sacc[f][0][r], sacc[f][1][r]), fmaxf(sacc[f][2][r], sacc[f][3][r]));
        mx = rowmax16(mx);
        float om = mrun[f][r];
        float nm = om;
        if (__any(mx > om)) {
          nm = fmaxf(om, mx);
          float sc = exp2f(om - nm);
#pragma unroll
          for (int c4 = 0; c4 < 4; ++c4) O[f][c4][r] *= sc;
          lrun[f][r] *= sc;
          mrun[f][r] = nm;
        }
        float p0 = exp2f(sacc[f][0][r] - nm);
        float p1 = exp2f(sacc[f][1][r] - nm);
        float p2 = exp2f(sacc[f][2][r] - nm);
        float p3 = exp2f(sacc[f][3][r] - nm);
        lrun[f][r] += rowsum16((p0 + p1) + (p2 + p3));
        int ro = (f * 16 + g * 4 + r) * 72;
        sP[w][ro + cc[0] + lr] = (u16)(__float_as_uint(p0) >> 16);
        sP[w][ro + cc[1] + lr] = (u16)(__float_as_uint(p1) >> 16);
        sP[w][ro + cc[2] + lr] = (u16)(__float_as_uint(p2) >> 16);
        sP[w][ro + cc[3] + lr] = (u16)(__float_as_uint(p3) >> 16);
      }

    // ---- O += P * V^T ----
    __builtin_amdgcn_s_setprio(1);
#pragma unroll
    for (int kk = 0; kk < 2; ++kk) {
      short8 ap[2];
#pragma unroll
      for (int f = 0; f < 2; ++f)
        ap[f] = *(const short8*)&sP[w][(f * 16 + lr) * 72 + (((kk * 2 + (g >> 1)) ^ bx) << 4) + ((g & 1) << 3)];
#pragma unroll
      for (int c4 = 0; c4 < 4; ++c4) {
        int row = c4 * 16 + lr;
        int sw = row & 7;
        short8 bv = *(const short8*)&sV[cur][row * 64 + (((kk * 4 + g) ^ sw) << 3)];
#pragma unroll
        for (int f = 0; f < 2; ++f)
          O[f][c4] = __builtin_amdgcn_mfma_f32_16x16x32_bf16(ap[f], bv, O[f][c4], 0, 0, 0);
      }
    }
    __builtin_amdgcn_s_setprio(0);

    __syncthreads();  // barrier B: staging landed, sV[cur] reads done
    cur ^= 1;
  }

  // ---- epilogue: normalized bf16 partial + (m, l) ----
  size_t pbase = (size_t)(bh * 2 + half) * QPAD;
#pragma unroll
  for (int f = 0; f < 2; ++f)
#pragma unroll
    for (int r = 0; r < 4; ++r) {
      int qg = qw + f * 16 + g * 4 + r;
      if (qg >= NTOK) continue;
      float inv = 1.f / lrun[f][r];
#pragma unroll
      for (int c4 = 0; c4 < 4; ++c4)
        Opart[(pbase + qg) * 64 + c4 * 16 + lr] = f2bf(O[f][c4][r] * inv);
      if (lr == 0) {
        ml[(pbase + qg) * 2]     = mrun[f][r];
        ml[(pbase + qg) * 2 + 1] = lrun[f][r];
      }
    }
}

// ---------------- combine halves + residual ----------------
__global__ __launch_bounds__(256) void k_comb(const u16* __restrict__ Opart,
                                              const float* __restrict__ ml,
                                              const u16* __restrict__ Qa,
                                              u16* __restrict__ outA) {
  const int wv = threadIdx.x >> 6, lane = threadIdx.x & 63;
  int rid = blockIdx.x * 4 + wv;
  if (rid >= BHN * NTOK) return;
  int bh = rid / NTOK, qg = rid - bh * NTOK;
  size_t base0 = (size_t)(bh * 2) * QPAD + qg;
  size_t base1 = base0 + QPAD;
  float m0 = ml[base0 * 2], l0 = ml[base0 * 2 + 1];
  float m1 = ml[base1 * 2], l1 = ml[base1 * 2 + 1];
  float M = fmaxf(m0, m1);
  float w0 = l0 * exp2f(m0 - M), w1 = l1 * exp2f(m1 - M);
  float inv = 1.f / (w0 + w1);
  float o0 = bf2f(Opart[base0 * 64 + lane]);
  float o1 = bf2f(Opart[base1 * 64 + lane]);
  float v = (w0 * o0 + w1 * o1) * inv;
  if (qg >= 1) v += RESID * bf2f(Qa[((size_t)bh * QPAD + qg) * AUG + lane]);
  int b = bh / HEADS, h = bh - b * HEADS;
  outA[((size_t)(b * NTOK + qg)) * DIM + h * HD + lane] = f2bf(v);
}

// ---------------- launch ----------------
extern "C" void kernel_launch(void* const* d_in, const int* in_sizes, int n_in,
                              void* d_out, int out_size, void* d_ws, size_t ws_size,
                              hipStream_t stream) {
  (void)in_sizes; (void)n_in; (void)out_size; (void)ws_size;
  const float* x      = (const float*)d_in[0];
  const float* qkv_w  = (const float*)d_in[1];
  const float* qkv_b  = (const float*)d_in[2];
  const float* proj_w = (const float*)d_in[3];
  const float* proj_b = (const float*)d_in[4];
  const float* pw_q   = (const float*)d_in[5];
  const float* pw_k   = (const float*)d_in[6];
  const float* pw_v   = (const float*)d_in[7];
  const float* nw_q   = (const float*)d_in[8];
  const float* nb_q   = (const float*)d_in[9];
  const float* nw_k   = (const float*)d_in[10];
  const float* nb_k   = (const float*)d_in[11];
  const float* nw_v   = (const float*)d_in[12];
  const float* nb_v   = (const float*)d_in[13];
  const float* rel_t  = (const float*)d_in[14];
  const float* rel_h  = (const float*)d_in[15];
  const float* rel_w  = (const float*)d_in[16];
  float* out = (float*)d_out;

  char* ws = (char*)d_ws;
  size_t off = 0;
  auto alloc = [&](size_t bytes) -> void* {
    off = (off + 511) & ~(size_t)511;
    void* p = ws + off;
    off += bytes;
    return p;
  };
  u16*   xb     = (u16*)alloc((size_t)MP * DIM * 2);
  u16*   qkvwT  = (u16*)alloc((size_t)DIM3 * DIM * 2);
  u16*   projwT = (u16*)alloc((size_t)DIM * DIM * 2);
  float* qkvf   = (float*)alloc((size_t)3 * BHN * NPAD * HD * 4);
  u16*   Qa     = (u16*)alloc((size_t)BHN * QPAD * AUG * 2);
  u16*   Ka     = (u16*)alloc((size_t)BHN * NPAD * AUG * 2);
  u16*   Vt     = (u16*)alloc((size_t)BHN * HD * NPAD * 2);
  u16*   attnO  = (u16*)alloc((size_t)MP * DIM * 2);
  u16*   Opart  = (u16*)alloc((size_t)BHN * 2 * QPAD * HD * 2);
  float* mlbuf  = (float*)alloc((size_t)BHN * 2 * QPAD * 2 * 4);

  k_cast_x<<<dim3(MP * DIM / 1024), dim3(256), 0, stream>>>(x, xb);
  k_transpose_cast<<<dim3((DIM3 / 32) * (DIM / 32)), dim3(256), 0, stream>>>(qkv_w, qkvwT, DIM, DIM3);
  k_transpose_cast<<<dim3((DIM / 32) * (DIM / 32)), dim3(256), 0, stream>>>(proj_w, projwT, DIM, DIM);

  k_gemm<0><<<dim3(MP / 128, DIM3 / 128), dim3(256), 0, stream>>>(xb, qkvwT, qkv_b, qkvf);

  k_pool<<<dim3(3 * BHN * 29), dim3(256), 0, stream>>>(
      qkvf, pw_q, pw_k, pw_v, nw_q, nb_q, nw_k, nb_k, nw_v, nb_v,
      Qa, Ka, Vt);

  k_rel<<<dim3(BHN * 25), dim3(256), 0, stream>>>(rel_t, rel_h, rel_w, Qa);

  k_attn<<<dim3(BHN * 26), dim3(256), 0, stream>>>(Qa, Ka, Vt, Opart, mlbuf);

  k_comb<<<dim3((BHN * NTOK + 3) / 4), dim3(256), 0, stream>>>(Opart, mlbuf, Qa, attnO);

  k_gemm<1><<<dim3(MP / 128, DIM / 128), dim3(256), 0, stream>>>(attnO, projwT, proj_b, out);
}

// Round 6
// 248.186 us; speedup vs baseline: 2.7090x; 1.1278x over previous
//
#include <hip/hip_runtime.h>
#include <cstdint>
#include <cstddef>

typedef __attribute__((ext_vector_type(8))) short short8;
typedef __attribute__((ext_vector_type(4))) short short4v;
typedef __attribute__((ext_vector_type(4))) float f32x4;
typedef unsigned short u16;

#define DI __device__ __forceinline__

// ---------------- problem constants ----------------
constexpr int BATCH = 4;
constexpr int HEADS = 12, HD = 64;
constexpr int NTOK = 1569;          // T*H*W + 1
constexpr int NPAD = 1600;          // kv pad (25*64), qkvf row pad
constexpr int QPAD = 1664;          // q pad (13*128)
constexpr int DIM = 768, DIM3 = 2304;
constexpr int MROWS = BATCH * NTOK; // 6276
constexpr int MP = 6400;            // 50 * 128
constexpr int AUG = 128;            // 64 ch + 8 + 14 + 14 + pad
constexpr int BHN = BATCH * HEADS;  // 48
constexpr float LOG2E = 1.4426950408889634f;
constexpr float QSCALE = 0.125f * LOG2E;  // attn scale folded with log2e (exp2 domain)
constexpr float RESID = 8.0f / LOG2E;     // 1/QSCALE
constexpr float LN_EPS = 1e-5f;

// ---------------- helpers ----------------
DI u16 f2bf(float x) {
  union { float f; unsigned u; } v; v.f = x;
  unsigned r = v.u + 0x7FFFu + ((v.u >> 16) & 1u);
  return (u16)(r >> 16);
}
DI float bf2f(u16 h) {
  union { unsigned u; float f; } v; v.u = ((unsigned)h) << 16;
  return v.f;
}

typedef const __attribute__((address_space(1))) unsigned int gu32;
typedef __attribute__((address_space(3))) unsigned int lu32;
DI void gld16(const void* g, void* l) {
  __builtin_amdgcn_global_load_lds((gu32*)g, (lu32*)l, 16, 0, 0);
}

// ---------------- cast kernels ----------------
__global__ __launch_bounds__(256) void k_cast_x(const float* __restrict__ x,
                                                u16* __restrict__ xb) {
  int i = (blockIdx.x * 256 + threadIdx.x) * 4;
  if (i >= MP * DIM) return;
  int row = i / DIM;
  short4v o;
  if (row < MROWS) {
    float4 v = *(const float4*)(x + i);
    o.x = (short)f2bf(v.x); o.y = (short)f2bf(v.y);
    o.z = (short)f2bf(v.z); o.w = (short)f2bf(v.w);
  } else {
    o.x = 0; o.y = 0; o.z = 0; o.w = 0;
  }
  *(short4v*)(xb + i) = o;
}

// dst (NC, K) bf16 = transpose of src (K, NC) f32 — LDS 32x32 tile transpose
__global__ __launch_bounds__(256) void k_transpose_cast(const float* __restrict__ src,
                                                        u16* __restrict__ dst,
                                                        int K, int NC) {
  __shared__ float tile[32][33];
  const int ntiles = NC >> 5;
  const int bx = blockIdx.x % ntiles;  // n-tile
  const int by = blockIdx.x / ntiles;  // k-tile
  const int tx = threadIdx.x & 31, ty = threadIdx.x >> 5;
  const int n0 = bx * 32, k0 = by * 32;
#pragma unroll
  for (int r = 0; r < 32; r += 8)
    tile[ty + r][tx] = src[(size_t)(k0 + ty + r) * NC + n0 + tx];
  __syncthreads();
#pragma unroll
  for (int r = 0; r < 32; r += 8)
    dst[(size_t)(n0 + ty + r) * K + k0 + tx] = f2bf(tile[tx][ty + r]);
}

// ---------------- GEMM: C(M,N) = A(M,768)*Bt(N,768)^T + bias ----------------
template <int EPI>
__global__ __launch_bounds__(256) void k_gemm(const u16* __restrict__ A,
                                              const u16* __restrict__ Bt,
                                              const float* __restrict__ bias,
                                              float* __restrict__ out) {
  __shared__ __align__(16) u16 sA[128 * 64];
  __shared__ __align__(16) u16 sB[128 * 64];
  const int tid = threadIdx.x;
  const int w = tid >> 6, lane = tid & 63;
  const int g = lane >> 4, lr = lane & 15;
  const int brow = blockIdx.x * 128, bcol = blockIdx.y * 128;
  const int wr = w >> 1, wc = w & 1;

  f32x4 acc[4][4];
#pragma unroll
  for (int m = 0; m < 4; ++m)
#pragma unroll
    for (int n = 0; n < 4; ++n) {
      acc[m][n].x = 0.f; acc[m][n].y = 0.f; acc[m][n].z = 0.f; acc[m][n].w = 0.f;
    }

  for (int kt = 0; kt < 12; ++kt) {
    __syncthreads();
#pragma unroll
    for (int j = 0; j < 4; ++j) {
      int cb = (j * 4 + w) * 64;
      int chunk = cb + lane;
      int row = chunk >> 3, ch = chunk & 7;
      int gch = ch ^ (row & 7);
      gld16(A + (size_t)(brow + row) * DIM + kt * 64 + gch * 8, &sA[cb * 8]);
      gld16(Bt + (size_t)(bcol + row) * DIM + kt * 64 + gch * 8, &sB[cb * 8]);
    }
    __syncthreads();

    short8 af[4][2], bfr[4][2];
#pragma unroll
    for (int m = 0; m < 4; ++m) {
      int row = wr * 64 + m * 16 + lr;
      int sw = row & 7;
#pragma unroll
      for (int ks = 0; ks < 2; ++ks)
        af[m][ks] = *(const short8*)&sA[row * 64 + (((ks * 4 + g) ^ sw) * 8)];
    }
#pragma unroll
    for (int n = 0; n < 4; ++n) {
      int row = wc * 64 + n * 16 + lr;
      int sw = row & 7;
#pragma unroll
      for (int ks = 0; ks < 2; ++ks)
        bfr[n][ks] = *(const short8*)&sB[row * 64 + (((ks * 4 + g) ^ sw) * 8)];
    }
#pragma unroll
    for (int m = 0; m < 4; ++m)
#pragma unroll
      for (int n = 0; n < 4; ++n) {
        acc[m][n] = __builtin_amdgcn_mfma_f32_16x16x32_bf16(af[m][0], bfr[n][0], acc[m][n], 0, 0, 0);
        acc[m][n] = __builtin_amdgcn_mfma_f32_16x16x32_bf16(af[m][1], bfr[n][1], acc[m][n], 0, 0, 0);
      }
  }

#pragma unroll
  for (int m = 0; m < 4; ++m)
#pragma unroll
    for (int n = 0; n < 4; ++n) {
      int gj = bcol + wc * 64 + n * 16 + lr;
      float bv = bias[gj];
#pragma unroll
      for (int r = 0; r < 4; ++r) {
        int gm = brow + wr * 64 + m * 16 + g * 4 + r;
        if (gm >= MROWS) continue;
        float v = acc[m][n][r] + bv;
        if (EPI == 0) {
          int t = gj >= 1536 ? 2 : (gj >= 768 ? 1 : 0);
          int rem = gj - t * 768;
          int h = rem >> 6, c = rem & 63;
          int b = gm >= 3 * NTOK ? 3 : (gm >= 2 * NTOK ? 2 : (gm >= NTOK ? 1 : 0));
          int nt = gm - b * NTOK;
          out[(((size_t)(t * BATCH + b) * HEADS + h) * NPAD + nt) * HD + c] = v;
        } else {
          out[(size_t)gm * DIM + gj] = v;
        }
      }
    }
}

// ---------------- pool (depthwise conv3d) + LN + aug writes ----------------
DI float ldsrc(const float* __restrict__ src, int tt, int h2, int w2, int lane) {
  if ((unsigned)tt >= 8u || (unsigned)h2 >= 14u || (unsigned)w2 >= 14u) return 0.f;
  return src[(size_t)(1 + (tt * 14 + h2) * 14 + w2) * HD + lane];
}

__global__ __launch_bounds__(256, 4) void k_pool(
    const float* __restrict__ qkv,
    const float* __restrict__ pw_q, const float* __restrict__ pw_k, const float* __restrict__ pw_v,
    const float* __restrict__ nw_q, const float* __restrict__ nb_q,
    const float* __restrict__ nw_k, const float* __restrict__ nb_k,
    const float* __restrict__ nw_v, const float* __restrict__ nb_v,
    u16* __restrict__ Qa, u16* __restrict__ Ka, u16* __restrict__ Vt) {
  const int wv = threadIdx.x >> 6, lane = threadIdx.x & 63;
  const int unit = blockIdx.x % 29;
  const int taubh = blockIdx.x / 29;
  const int tau = taubh / BHN, bh = taubh % BHN;
  const float* src = qkv + ((size_t)tau * BHN + bh) * ((size_t)NPAD * HD);
  const float* nw = tau == 0 ? nw_q : tau == 1 ? nw_k : nw_v;
  const float* nb = tau == 0 ? nb_q : tau == 1 ? nb_k : nb_v;

  if (unit == 28) {
    if (wv == 0) {
      // CLS token (n = 0)
      float val = src[lane];
      float s = val, sq = val * val;
#pragma unroll
      for (int off = 1; off < 64; off <<= 1) { s += __shfl_xor(s, off); sq += __shfl_xor(sq, off); }
      float mean = s * (1.f / 64.f);
      float var = sq * (1.f / 64.f) - mean * mean;
      float ln = (val - mean) * rsqrtf(var + LN_EPS) * nw[lane] + nb[lane];
      if (tau == 0)      { size_t base = (size_t)bh * QPAD * AUG; Qa[base + lane] = f2bf(ln * QSCALE); Qa[base + 64 + lane] = 0; }
      else if (tau == 1) { size_t base = (size_t)bh * NPAD * AUG; Ka[base + lane] = f2bf(ln); Ka[base + 64 + lane] = 0; }
      else               { Vt[((size_t)bh * HD + lane) * NPAD] = f2bf(ln); }
    } else {
      // pad rows -> zero (Qa to QPAD, Ka/Vt to NPAD)
      int lim = (tau == 0) ? QPAD : NPAD;
      for (int n = 1569 + (wv - 1); n < lim; n += 3) {
        if (tau == 0) {
          size_t base = ((size_t)bh * QPAD + n) * AUG;
          Qa[base + lane] = 0; Qa[base + 64 + lane] = 0;
        } else if (tau == 1) {
          size_t base = ((size_t)bh * NPAD + n) * AUG;
          Ka[base + lane] = 0; Ka[base + 64 + lane] = 0;
        } else {
          Vt[((size_t)bh * HD + lane) * NPAD + n] = 0;
        }
      }
    }
    return;
  }

  const int th = unit * 4 + wv;          // 0..111
  const int t = th / 14, hh = th % 14;

  float wt[27];
  {
    const float* wp = (tau == 0 ? pw_q : tau == 1 ? pw_k : pw_v) + lane * 27;
#pragma unroll
    for (int j = 0; j < 27; ++j) wt[j] = wp[j];
  }

  float win[9][3];
#pragma unroll
  for (int dt = 0; dt < 3; ++dt)
#pragma unroll
    for (int dh = 0; dh < 3; ++dh) {
      win[dt * 3 + dh][0] = 0.f;
      win[dt * 3 + dh][1] = ldsrc(src, t + dt - 1, hh + dh - 1, 0, lane);
      win[dt * 3 + dh][2] = ldsrc(src, t + dt - 1, hh + dh - 1, 1, lane);
    }

#pragma unroll
  for (int ww = 0; ww < 14; ++ww) {
    float nxt[9];
#pragma unroll
    for (int dt = 0; dt < 3; ++dt)
#pragma unroll
      for (int dh = 0; dh < 3; ++dh)
        nxt[dt * 3 + dh] = ldsrc(src, t + dt - 1, hh + dh - 1, ww + 2, lane);

    float a = 0.f;
#pragma unroll
    for (int i = 0; i < 9; ++i)
      a += win[i][0] * wt[i * 3 + 0] + win[i][1] * wt[i * 3 + 1] + win[i][2] * wt[i * 3 + 2];

    float s = a, sq = a * a;
#pragma unroll
    for (int off = 1; off < 64; off <<= 1) { s += __shfl_xor(s, off); sq += __shfl_xor(sq, off); }
    float mean = s * (1.f / 64.f);
    float var = sq * (1.f / 64.f) - mean * mean;
    float ln = (a - mean) * rsqrtf(var + LN_EPS) * nw[lane] + nb[lane];

    const int n = 1 + (t * 14 + hh) * 14 + ww;
    if (tau == 0) {
      size_t base = ((size_t)bh * QPAD + n) * AUG;
      Qa[base + lane] = f2bf(ln * QSCALE);
      Qa[base + 64 + lane] = 0;  // k_rel fills lanes 64..99
    } else if (tau == 1) {
      size_t base = ((size_t)bh * NPAD + n) * AUG;
      Ka[base + lane] = f2bf(ln);
      u16 e = 0;
      if (lane == t || lane == 8 + hh || lane == 22 + ww) e = 0x3F80;  // bf16 1.0
      Ka[base + 64 + lane] = e;
    } else {
      Vt[((size_t)bh * HD + lane) * NPAD + n] = f2bf(ln);
    }

#pragma unroll
    for (int i = 0; i < 9; ++i) { win[i][0] = win[i][1]; win[i][1] = win[i][2]; win[i][2] = nxt[i]; }
  }
}

// ---------------- rel-pos dot table via MFMA ----------------
__global__ __launch_bounds__(256) void k_rel(const float* __restrict__ rel_t,
                                             const float* __restrict__ rel_h,
                                             const float* __restrict__ rel_w,
                                             u16* __restrict__ Qa) {
  __shared__ __align__(16) u16 sR[80 * 72];
  const int tid = threadIdx.x, w = tid >> 6, lane = tid & 63;
  const int g = lane >> 4, lr = lane & 15;
  const int bh = blockIdx.x / 25, qt = blockIdx.x % 25;

  for (int idx = tid; idx < 80 * 64; idx += 256) {
    int j = idx >> 6, c = idx & 63;
    float v = 0.f;
    if (j < 15)      v = rel_t[j * HD + c];
    else if (j < 42) v = rel_h[(j - 15) * HD + c];
    else if (j < 69) v = rel_w[(j - 42) * HD + c];
    sR[j * 72 + c] = f2bf(v * 8.f);
  }
  __syncthreads();

  const int q0 = qt * 64 + w * 16;
  short8 aq[2];
  {
    const u16* qrow = Qa + ((size_t)bh * QPAD + q0 + lr) * AUG;
    aq[0] = *(const short8*)(qrow + g * 8);
    aq[1] = *(const short8*)(qrow + 32 + g * 8);
  }

  f32x4 acc[5];
#pragma unroll
  for (int jt = 0; jt < 5; ++jt) {
    f32x4 a; a.x = 0.f; a.y = 0.f; a.z = 0.f; a.w = 0.f;
    int row = jt * 16 + lr;
    short8 b0 = *(const short8*)&sR[row * 72 + g * 8];
    short8 b1 = *(const short8*)&sR[row * 72 + (4 + g) * 8];
    a = __builtin_amdgcn_mfma_f32_16x16x32_bf16(aq[0], b0, a, 0, 0, 0);
    a = __builtin_amdgcn_mfma_f32_16x16x32_bf16(aq[1], b1, a, 0, 0, 0);
    acc[jt] = a;
  }

#pragma unroll
  for (int jt = 0; jt < 5; ++jt) {
    int j = jt * 16 + lr;
#pragma unroll
    for (int r = 0; r < 4; ++r) {
      int gq = q0 + g * 4 + r;
      if (gq < 1 || gq >= NTOK) continue;
      int p = gq - 1;
      int t = p / 196, pr = p - t * 196;
      int hh = pr / 14, ww = pr - hh * 14;
      int it = t + 7 - j;
      int ih = hh + 28 - j;
      int iw = ww + 55 - j;
      int i = -1;
      if ((unsigned)it < 8u) i = it;
      else if ((unsigned)ih < 14u) i = 8 + ih;
      else if ((unsigned)iw < 14u) i = 22 + iw;
      if (i >= 0)
        Qa[((size_t)bh * QPAD + gq) * AUG + 64 + i] = f2bf(acc[jt][r]);
    }
  }
}

// ---------------- fused flash attention (KV-split x2, swapped QK, no max-tracking) ----------------
// Without max subtraction (scores bounded), partials are in a common absolute
// scale: P = exp2(S), l = sum P. k_comb merges by pure l-weighting.
__global__ __launch_bounds__(256, 3) void k_attn(const u16* __restrict__ Qa,
                                                 const u16* __restrict__ Ka,
                                                 const u16* __restrict__ Vt,
                                                 u16* __restrict__ Opart,
                                                 float* __restrict__ lsum) {
  __shared__ __align__(16) u16 sK[64 * 128];     // K_aug tile, single-buffered
  __shared__ __align__(16) u16 sV[2][64 * 64];   // V^T tile, double-buffered
  __shared__ __align__(16) u16 sP[4][32 * 72];   // per-wave P [q][key], stride 72
  const int tid = threadIdx.x, w = tid >> 6, lane = tid & 63;
  const int g = lane >> 4, lr = lane & 15;
  const int bid = blockIdx.x;
  const int swz = (bid & 7) * 156 + (bid >> 3);  // XCD-chunked (1248 = 8*156)
  const int bh = swz / 26, rem2 = swz % 26;
  const int half = rem2 / 13, qt = rem2 % 13;
  const int qw = qt * 128 + w * 32;
  const int kb0 = half * 13;
  const int kbN = half ? 12 : 13;

  // Q fragments (registers, whole loop)
  short8 aq[2][4];
#pragma unroll
  for (int f = 0; f < 2; ++f) {
    const u16* qrow = Qa + ((size_t)bh * QPAD + qw + f * 16 + lr) * AUG;
#pragma unroll
    for (int ks = 0; ks < 4; ++ks) aq[f][ks] = *(const short8*)(qrow + ks * 32 + g * 8);
  }

  // constant all-ones B-frag (bf16 1.0) for the l row-sum MFMA
  short8 vones;
#pragma unroll
  for (int i = 0; i < 8; ++i) vones[i] = (short)0x3F80;

  // hoisted staging pointers
  const u16* kgp[4];
  u16* kld[4];
#pragma unroll
  for (int j = 0; j < 4; ++j) {
    int idx = j * 256 + tid;
    int row = idx >> 4, ch = idx & 15;
    int gch = ch ^ (row & 7);
    kgp[j] = Ka + ((size_t)bh * NPAD + kb0 * 64 + row) * AUG + gch * 8;
    kld[j] = &sK[(j * 256 + w * 64) * 8];
  }
  const u16* vgp[2];
  int vld[2];
#pragma unroll
  for (int j = 0; j < 2; ++j) {
    int idx = j * 256 + tid;
    int row = idx >> 3, ch = idx & 7;
    int gch = ch ^ (row & 7);
    vgp[j] = Vt + ((size_t)bh * HD + row) * NPAD + kb0 * 64 + gch * 8;
    vld[j] = (j * 256 + w * 64) * 8;
  }

  // prologue stage
#pragma unroll
  for (int j = 0; j < 4; ++j) { gld16(kgp[j], kld[j]); kgp[j] += 64 * AUG; }
#pragma unroll
  for (int j = 0; j < 2; ++j) { gld16(vgp[j], &sV[0][vld[j]]); vgp[j] += 64; }
  __syncthreads();

  f32x4 O[2][5];
#pragma unroll
  for (int f = 0; f < 2; ++f)
#pragma unroll
    for (int c4 = 0; c4 < 5; ++c4) { O[f][c4].x = 0.f; O[f][c4].y = 0.f; O[f][c4].z = 0.f; O[f][c4].w = 0.f; }

  int cur = 0;
  for (int it = 0; it < kbN; ++it) {
    // ---- S^T = K * Q^T (swapped: D row = key = g*4+r, col = q = lr) ----
    f32x4 sacc[2][4];
    __builtin_amdgcn_s_setprio(1);
#pragma unroll
    for (int ct = 0; ct < 4; ++ct) {
      int row = ct * 16 + lr;
      int sw = row & 7;
      short8 bk[4];
#pragma unroll
      for (int ks = 0; ks < 4; ++ks)
        bk[ks] = *(const short8*)&sK[row * 128 + (((ks * 4 + g) ^ sw) << 3)];
#pragma unroll
      for (int f = 0; f < 2; ++f) {
        f32x4 a; a.x = 0.f; a.y = 0.f; a.z = 0.f; a.w = 0.f;
#pragma unroll
        for (int ks = 0; ks < 4; ++ks)
          a = __builtin_amdgcn_mfma_f32_16x16x32_bf16(bk[ks], aq[f][ks], a, 0, 0, 0);
        sacc[f][ct] = a;
      }
    }
    __builtin_amdgcn_s_setprio(0);
    __syncthreads();  // barrier A: all QK reads of sK done

    // stage next tile
    if (it + 1 < kbN) {
#pragma unroll
      for (int j = 0; j < 4; ++j) { gld16(kgp[j], kld[j]); kgp[j] += 64 * AUG; }
#pragma unroll
      for (int j = 0; j < 2; ++j) { gld16(vgp[j], &sV[cur ^ 1][vld[j]]); vgp[j] += 64; }
    }

    if (kb0 + it == 24) {  // tail: local keys >= 33 invalid (key = ct*16+g*4+r)
#pragma unroll
      for (int f = 0; f < 2; ++f) {
        sacc[f][2][0] = (g == 0) ? sacc[f][2][0] : -1e30f;
        sacc[f][2][1] = -1e30f; sacc[f][2][2] = -1e30f; sacc[f][2][3] = -1e30f;
        sacc[f][3][0] = -1e30f; sacc[f][3][1] = -1e30f;
        sacc[f][3][2] = -1e30f; sacc[f][3][3] = -1e30f;
      }
    }

    // ---- P = exp2(S), pack 4 consecutive keys -> b64 LDS write ----
#pragma unroll
    for (int f = 0; f < 2; ++f) {
      int ro = (f * 16 + lr) * 72;
#pragma unroll
      for (int ct = 0; ct < 4; ++ct) {
        unsigned u0 = __float_as_uint(exp2f(sacc[f][ct][0]));
        unsigned u1 = __float_as_uint(exp2f(sacc[f][ct][1]));
        unsigned u2 = __float_as_uint(exp2f(sacc[f][ct][2]));
        unsigned u3 = __float_as_uint(exp2f(sacc[f][ct][3]));
        uint2 pk;
        pk.x = __builtin_amdgcn_perm(u1, u0, 0x07060302u);  // [bf(u0), bf(u1)]
        pk.y = __builtin_amdgcn_perm(u3, u2, 0x07060302u);  // [bf(u2), bf(u3)]
        *(uint2*)&sP[w][ro + ct * 16 + g * 4] = pk;
      }
    }

    // ---- O += P * V^T (c4=4 vs ones-frag accumulates l in every column) ----
    __builtin_amdgcn_s_setprio(1);
#pragma unroll
    for (int kk = 0; kk < 2; ++kk) {
      short8 ap[2];
#pragma unroll
      for (int f = 0; f < 2; ++f)
        ap[f] = *(const short8*)&sP[w][(f * 16 + lr) * 72 + kk * 32 + g * 8];
#pragma unroll
      for (int c4 = 0; c4 < 4; ++c4) {
        int row = c4 * 16 + lr;
        int sw = row & 7;
        short8 bv = *(const short8*)&sV[cur][row * 64 + (((kk * 4 + g) ^ sw) << 3)];
#pragma unroll
        for (int f = 0; f < 2; ++f)
          O[f][c4] = __builtin_amdgcn_mfma_f32_16x16x32_bf16(ap[f], bv, O[f][c4], 0, 0, 0);
      }
#pragma unroll
      for (int f = 0; f < 2; ++f)
        O[f][4] = __builtin_amdgcn_mfma_f32_16x16x32_bf16(ap[f], vones, O[f][4], 0, 0, 0);
    }
    __builtin_amdgcn_s_setprio(0);

    __syncthreads();  // barrier B: staging landed, sV[cur] reads done
    cur ^= 1;
  }

  // ---- epilogue: normalized bf16 partial + l ----
  size_t pbase = (size_t)(bh * 2 + half) * QPAD;
#pragma unroll
  for (int f = 0; f < 2; ++f)
#pragma unroll
    for (int r = 0; r < 4; ++r) {
      int qg = qw + f * 16 + g * 4 + r;
      if (qg >= NTOK) continue;
      float l = O[f][4][r];   // identical across all 16 columns
      float inv = 1.f / l;
#pragma unroll
      for (int c4 = 0; c4 < 4; ++c4)
        Opart[(pbase + qg) * 64 + c4 * 16 + lr] = f2bf(O[f][c4][r] * inv);
      if (lr == 0) lsum[pbase + qg] = l;
    }
}

// ---------------- combine halves + residual (pure l-weighting) ----------------
__global__ __launch_bounds__(256) void k_comb(const u16* __restrict__ Opart,
                                              const float* __restrict__ lsum,
                                              const u16* __restrict__ Qa,
                                              u16* __restrict__ outA) {
  const int wv = threadIdx.x >> 6, lane = threadIdx.x & 63;
  int rid = blockIdx.x * 4 + wv;
  if (rid >= BHN * NTOK) return;
  int bh = rid / NTOK, qg = rid - bh * NTOK;
  size_t base0 = (size_t)(bh * 2) * QPAD + qg;
  size_t base1 = base0 + QPAD;
  float l0 = lsum[base0], l1 = lsum[base1];
  float inv = 1.f / (l0 + l1);
  float o0 = bf2f(Opart[base0 * 64 + lane]);
  float o1 = bf2f(Opart[base1 * 64 + lane]);
  float v = (l0 * o0 + l1 * o1) * inv;
  if (qg >= 1) v += RESID * bf2f(Qa[((size_t)bh * QPAD + qg) * AUG + lane]);
  int b = bh / HEADS, h = bh - b * HEADS;
  outA[((size_t)(b * NTOK + qg)) * DIM + h * HD + lane] = f2bf(v);
}

// ---------------- launch ----------------
extern "C" void kernel_launch(void* const* d_in, const int* in_sizes, int n_in,
                              void* d_out, int out_size, void* d_ws, size_t ws_size,
                              hipStream_t stream) {
  (void)in_sizes; (void)n_in; (void)out_size; (void)ws_size;
  const float* x      = (const float*)d_in[0];
  const float* qkv_w  = (const float*)d_in[1];
  const float* qkv_b  = (const float*)d_in[2];
  const float* proj_w = (const float*)d_in[3];
  const float* proj_b = (const float*)d_in[4];
  const float* pw_q   = (const float*)d_in[5];
  const float* pw_k   = (const float*)d_in[6];
  const float* pw_v   = (const float*)d_in[7];
  const float* nw_q   = (const float*)d_in[8];
  const float* nb_q   = (const float*)d_in[9];
  const float* nw_k   = (const float*)d_in[10];
  const float* nb_k   = (const float*)d_in[11];
  const float* nw_v   = (const float*)d_in[12];
  const float* nb_v   = (const float*)d_in[13];
  const float* rel_t  = (const float*)d_in[14];
  const float* rel_h  = (const float*)d_in[15];
  const float* rel_w  = (const float*)d_in[16];
  float* out = (float*)d_out;

  char* ws = (char*)d_ws;
  size_t off = 0;
  auto alloc = [&](size_t bytes) -> void* {
    off = (off + 511) & ~(size_t)511;
    void* p = ws + off;
    off += bytes;
    return p;
  };
  u16*   xb     = (u16*)alloc((size_t)MP * DIM * 2);
  u16*   qkvwT  = (u16*)alloc((size_t)DIM3 * DIM * 2);
  u16*   projwT = (u16*)alloc((size_t)DIM * DIM * 2);
  float* qkvf   = (float*)alloc((size_t)3 * BHN * NPAD * HD * 4);
  u16*   Qa     = (u16*)alloc((size_t)BHN * QPAD * AUG * 2);
  u16*   Ka     = (u16*)alloc((size_t)BHN * NPAD * AUG * 2);
  u16*   Vt     = (u16*)alloc((size_t)BHN * HD * NPAD * 2);
  u16*   attnO  = (u16*)alloc((size_t)MP * DIM * 2);
  u16*   Opart  = (u16*)alloc((size_t)BHN * 2 * QPAD * HD * 2);
  float* lbuf   = (float*)alloc((size_t)BHN * 2 * QPAD * 4);

  k_cast_x<<<dim3(MP * DIM / 1024), dim3(256), 0, stream>>>(x, xb);
  k_transpose_cast<<<dim3((DIM3 / 32) * (DIM / 32)), dim3(256), 0, stream>>>(qkv_w, qkvwT, DIM, DIM3);
  k_transpose_cast<<<dim3((DIM / 32) * (DIM / 32)), dim3(256), 0, stream>>>(proj_w, projwT, DIM, DIM);

  k_gemm<0><<<dim3(MP / 128, DIM3 / 128), dim3(256), 0, stream>>>(xb, qkvwT, qkv_b, qkvf);

  k_pool<<<dim3(3 * BHN * 29), dim3(256), 0, stream>>>(
      qkvf, pw_q, pw_k, pw_v, nw_q, nb_q, nw_k, nb_k, nw_v, nb_v,
      Qa, Ka, Vt);

  k_rel<<<dim3(BHN * 25), dim3(256), 0, stream>>>(rel_t, rel_h, rel_w, Qa);

  k_attn<<<dim3(BHN * 26), dim3(256), 0, stream>>>(Qa, Ka, Vt, Opart, lbuf);

  k_comb<<<dim3((BHN * NTOK + 3) / 4), dim3(256), 0, stream>>>(Opart, lbuf, Qa, attnO);

  k_gemm<1><<<dim3(MP / 128, DIM / 128), dim3(256), 0, stream>>>(attnO, projwT, proj_b, out);
}